// Round 2
// baseline (1237.741 us; speedup 1.0000x reference)
//
#include <hip/hip_runtime.h>

// ---------------------------------------------------------------------------
// SPPF + criss-cross attention, MI355X bf16-MFMA pipeline.
// Layout convention: "position-major" activations  (B*H*W, C) row-major.
// Workspace budget: 229,638,144 bytes (219 MiB). qk lives in d_out (scratch
// until the final transpose overwrites it).
// ---------------------------------------------------------------------------

typedef short bf16x8 __attribute__((ext_vector_type(8)));
typedef float f32x4  __attribute__((ext_vector_type(4)));

#define DEV __device__ __forceinline__

DEV float bf2f(unsigned short u) {
    unsigned int i = ((unsigned int)u) << 16;
    float f; __builtin_memcpy(&f, &i, 4); return f;
}
DEV unsigned short f2bf(float f) {
    unsigned int i; __builtin_memcpy(&i, &f, 4);
    unsigned int r = i + 0x7FFFu + ((i >> 16) & 1u);
    return (unsigned short)(r >> 16);
}
DEV float fsilu(float v) { return v / (1.f + __expf(-v)); }

// global -> LDS async copy, 16B per lane. LDS base must be wave-uniform.
#define GLL(gsrc, ldst)                                                        \
    __builtin_amdgcn_global_load_lds(                                          \
        (const __attribute__((address_space(1))) unsigned int*)(gsrc),         \
        (__attribute__((address_space(3))) unsigned int*)(ldst), 16, 0, 0)

#define MFMA(a, b, c) __builtin_amdgcn_mfma_f32_16x16x32_bf16((a), (b), (c), 0, 0, 0)

// ---------------------------------------------------------------------------
// prep: fp32 weights -> bf16, stacked/padded qk weights, BN scale/shift vecs
// ---------------------------------------------------------------------------
__global__ __launch_bounds__(256) void prep_kernel(
    const float* __restrict__ cv1_w, const float* __restrict__ cv1_g,
    const float* __restrict__ cv1_b, const float* __restrict__ cv1_m,
    const float* __restrict__ cv1_v,
    const float* __restrict__ q_w, const float* __restrict__ q_b,
    const float* __restrict__ k_w, const float* __restrict__ k_b,
    const float* __restrict__ v_w,
    const float* __restrict__ cv2_w, const float* __restrict__ cv2_g,
    const float* __restrict__ cv2_b, const float* __restrict__ cv2_m,
    const float* __restrict__ cv2_v,
    unsigned short* __restrict__ wb1, unsigned short* __restrict__ wqk,
    unsigned short* __restrict__ wv, unsigned short* __restrict__ wc2,
    float* __restrict__ sc1, float* __restrict__ sh1,
    float* __restrict__ sc2, float* __restrict__ sh2,
    float* __restrict__ qkb)
{
    for (int i = blockIdx.x * 256 + threadIdx.x; i < 3211264;
         i += gridDim.x * 256) {
        wv[i] = f2bf(v_w[i]);
        if (i < 917504) {
            wc2[i] = f2bf(cv2_w[i]);
            int row = i / 1792;
            int col = i - row * 1792;
            float qv = (row < 224) ? q_w[i]
                       : (row < 448) ? k_w[(row - 224) * 1792 + col] : 0.f;
            wqk[i] = f2bf(qv);
        }
        if (i < 131072) wb1[i] = f2bf(cv1_w[i]);
        if (i < 512) {
            qkb[i] = (i < 224) ? q_b[i] : (i < 448 ? k_b[i - 224] : 0.f);
            float sc = cv2_g[i] * rsqrtf(cv2_v[i] + 1e-5f);
            sc2[i] = sc; sh2[i] = cv2_b[i] - cv2_m[i] * sc;
        }
        if (i < 256) {
            float sc = cv1_g[i] * rsqrtf(cv1_v[i] + 1e-5f);
            sc1[i] = sc; sh1[i] = cv1_b[i] - cv1_m[i] * sc;
        }
    }
}

// ---------------------------------------------------------------------------
// transpose x (8,512,4096) fp32  ->  xT (32768, 512) bf16
// ---------------------------------------------------------------------------
__global__ __launch_bounds__(256) void transpose_x(
    const float* __restrict__ x, unsigned short* __restrict__ xT)
{
    int bid = blockIdx.x;               // 8 * 8 * 64 = 4096 blocks
    int nt = bid & 63, ct = (bid >> 6) & 7, b = bid >> 9;
    __shared__ float tile[64][65];
    int tid = threadIdx.x;
    int n0 = nt * 64, c0 = ct * 64;
#pragma unroll
    for (int it = 0; it < 16; ++it) {
        int idx = tid + it * 256;
        int r = idx >> 6, cc = idx & 63;          // r = c-local, cc = n-local
        tile[r][cc] = x[((long)(b * 512 + c0 + r)) * 4096 + n0 + cc];
    }
    __syncthreads();
#pragma unroll
    for (int it = 0; it < 16; ++it) {
        int idx = tid + it * 256;
        int r = idx >> 6, cc = idx & 63;          // r = n-local, cc = c-local
        xT[((long)(b * 4096 + n0 + r)) * 512 + c0 + cc] = f2bf(tile[cc][r]);
    }
}

// ---------------------------------------------------------------------------
// transpose cv2tmp (32768,512) fp32 -> d_out (8,512,4096) fp32
// ---------------------------------------------------------------------------
__global__ __launch_bounds__(256) void transpose_out(
    const float* __restrict__ t, float* __restrict__ outp)
{
    int bid = blockIdx.x;               // 8 * 8 * 64 = 4096 blocks
    int nt = bid & 63, ot = (bid >> 6) & 7, b = bid >> 9;
    __shared__ float tile[64][65];
    int tid = threadIdx.x;
    int n0 = nt * 64, o0 = ot * 64;
#pragma unroll
    for (int it = 0; it < 16; ++it) {
        int idx = tid + it * 256;
        int r = idx >> 6, cc = idx & 63;          // r = n-local, cc = o-local
        tile[r][cc] = t[((long)(b * 4096 + n0 + r)) * 512 + o0 + cc];
    }
    __syncthreads();
#pragma unroll
    for (int it = 0; it < 16; ++it) {
        int idx = tid + it * 256;
        int r = idx >> 6, cc = idx & 63;          // r = o-local, cc = n-local
        outp[((long)(b * 512 + o0 + r)) * 4096 + n0 + cc] = tile[cc][r];
    }
}

// ---------------------------------------------------------------------------
// NT GEMM, m97-style 128x128 tile, BK=32, 4 waves (2x2), 16x16x32 bf16 MFMA.
// C[m,n] = sum_k A[m,k]*B[n,k].  A = activations (M=positions), B = weights.
// EPI: 0 = BN+SiLU -> bf16, 1 = +bias -> bf16, 2 = BN+SiLU -> fp32
// ---------------------------------------------------------------------------
template <int EPI>
__global__ __launch_bounds__(256) void gemm_nt(
    const unsigned short* __restrict__ A, int lda,
    const unsigned short* __restrict__ B, int ldb,
    int K, void* __restrict__ outp, int ldo,
    const float* __restrict__ p0, const float* __restrict__ p1)
{
    __shared__ __align__(16) unsigned short Ash[128 * 32];
    __shared__ __align__(16) unsigned short Bsh[128 * 32];
    const int tid = threadIdx.x;
    const int lane = tid & 63, wave = tid >> 6;
    const int wm = wave & 1, wn = wave >> 1;
    const long tile_m = (long)blockIdx.x * 128;
    const int tile_n = blockIdx.y * 128;
    f32x4 acc[4][4] = {};
    const int nsteps = K >> 5;
    // staging geometry: wave w stages bytes [w*2048, w*2048+2048) of each tile
    const int o0 = wave * 2048 + lane * 16;
    const int r0 = o0 >> 6, kk0 = (o0 & 63) >> 1;
    const int o1 = o0 + 1024;
    const int r1 = o1 >> 6, kk1 = (o1 & 63) >> 1;
    const unsigned short* Ab0 = A + (tile_m + r0) * (long)lda + kk0;
    const unsigned short* Ab1 = A + (tile_m + r1) * (long)lda + kk1;
    const unsigned short* Bb0 = B + (long)(tile_n + r0) * ldb + kk0;
    const unsigned short* Bb1 = B + (long)(tile_n + r1) * ldb + kk1;
    unsigned short* Ad0 = Ash + wave * 1024;
    unsigned short* Ad1 = Ash + wave * 1024 + 512;
    unsigned short* Bd0 = Bsh + wave * 1024;
    unsigned short* Bd1 = Bsh + wave * 1024 + 512;
    const int arow = lane & 15;
    const int kcol = (lane >> 4) << 3;
    for (int kt = 0; kt < nsteps; ++kt) {
        __syncthreads();
        const int ke = kt << 5;
        GLL(Ab0 + ke, Ad0);
        GLL(Ab1 + ke, Ad1);
        GLL(Bb0 + ke, Bd0);
        GLL(Bb1 + ke, Bd1);
        __syncthreads();
        bf16x8 af[4], bfv[4];
#pragma unroll
        for (int m = 0; m < 4; ++m)
            af[m] = *(const bf16x8*)(Ash + (wm * 64 + m * 16 + arow) * 32 + kcol);
#pragma unroll
        for (int n = 0; n < 4; ++n)
            bfv[n] = *(const bf16x8*)(Bsh + (wn * 64 + n * 16 + arow) * 32 + kcol);
#pragma unroll
        for (int m = 0; m < 4; ++m)
#pragma unroll
            for (int n = 0; n < 4; ++n)
                acc[m][n] = MFMA(af[m], bfv[n], acc[m][n]);
    }
    // epilogue
    const int rbase = (lane >> 4) << 2;
    const int cbase = lane & 15;
#pragma unroll
    for (int n = 0; n < 4; ++n) {
        const int gcol = tile_n + wn * 64 + n * 16 + cbase;
        const float s0 = p0[gcol];
        const float s1 = (EPI != 1) ? p1[gcol] : 0.f;
#pragma unroll
        for (int m = 0; m < 4; ++m) {
#pragma unroll
            for (int r = 0; r < 4; ++r) {
                const long grow = tile_m + wm * 64 + m * 16 + rbase + r;
                float v = acc[m][n][r];
                if (EPI != 1) { v = v * s0 + s1; v = fsilu(v); }
                else          { v += s0; }
                if (EPI == 2) ((float*)outp)[grow * ldo + gcol] = v;
                else ((unsigned short*)outp)[grow * ldo + gcol] = f2bf(v);
            }
        }
    }
}

// ---------------------------------------------------------------------------
// P1: horizontal (along w) pooling pass. block = (b,h). Produces row-pass
// rmax5/rowmax9/rowmax13, rsum5/rsum9/rsum13 into pool planes (32768x256 ea).
// Windowed sums kept in registers (incremental sliding window); LDS = 64 KB.
// ---------------------------------------------------------------------------
__global__ __launch_bounds__(256) void pool_h(
    const unsigned short* __restrict__ catT, unsigned short* __restrict__ pool)
{
    const int b = blockIdx.x >> 6, h = blockIdx.x & 63;
    __shared__ __align__(16) unsigned short x1s[64 * 256];
    __shared__ __align__(16) unsigned short rm5[64 * 256];
    const int tid = threadIdx.x, lane = tid & 63, wave = tid >> 6;
    const long nb = (long)b * 4096 + h * 64;
    // stage x1 slab (x1 = catT cols [0,256))
#pragma unroll
    for (int j = 0; j < 8; ++j) {
        int o = wave * 8192 + j * 1024 + lane * 16;   // byte offset in slab
        int w = o >> 9, c = (o & 511) >> 1;
        GLL(catT + (nb + w) * 1792 + c,
            (char*)x1s + (wave * 8192 + j * 1024));
    }
    __syncthreads();
    const int c = tid;   // one channel per thread; column-private below
    for (int w = 0; w < 64; ++w) {
        int lo = (w >= 2) ? w - 2 : 0, hi = (w <= 61) ? w + 2 : 63;
        float m = bf2f(x1s[lo * 256 + c]);
        for (int d = lo + 1; d <= hi; ++d) m = fmaxf(m, bf2f(x1s[d * 256 + c]));
        rm5[w * 256 + c] = f2bf(m);
    }
    float s5 = 0.f, s9 = 0.f, s13 = 0.f;
#pragma unroll
    for (int d = 0; d <= 2; ++d) s5  += bf2f(x1s[d * 256 + c]);
#pragma unroll
    for (int d = 0; d <= 4; ++d) s9  += bf2f(x1s[d * 256 + c]);
#pragma unroll
    for (int d = 0; d <= 6; ++d) s13 += bf2f(x1s[d * 256 + c]);
    unsigned short* q0 = pool;
    unsigned short* q1 = pool + (long)32768 * 256;
    unsigned short* q2 = pool + (long)32768 * 512;
    unsigned short* q3 = pool + (long)32768 * 768;
    unsigned short* q4 = pool + (long)32768 * 1024;
    unsigned short* q5 = pool + (long)32768 * 1280;
    for (int w = 0; w < 64; ++w) {
        long off = (nb + w) * 256 + c;
        float v5 = bf2f(rm5[w * 256 + c]);
        int wm2 = (w >= 2) ? w - 2 : 0, wp2 = (w <= 61) ? w + 2 : 63;
        int wm4 = (w >= 4) ? w - 4 : 0, wp4 = (w <= 59) ? w + 4 : 63;
        float v9  = fmaxf(bf2f(rm5[wm2 * 256 + c]), bf2f(rm5[wp2 * 256 + c]));
        float v13 = fmaxf(v5, fmaxf(bf2f(rm5[wm4 * 256 + c]),
                                    bf2f(rm5[wp4 * 256 + c])));
        q0[off] = f2bf(v5);  q1[off] = f2bf(v9);  q2[off] = f2bf(v13);
        q3[off] = f2bf(s5);  q4[off] = f2bf(s9);  q5[off] = f2bf(s13);
        // advance clamped windows to w+1
        if (w + 3 <= 63) s5  += bf2f(x1s[(w + 3) * 256 + c]);
        if (w - 2 >= 0)  s5  -= bf2f(x1s[(w - 2) * 256 + c]);
        if (w + 5 <= 63) s9  += bf2f(x1s[(w + 5) * 256 + c]);
        if (w - 4 >= 0)  s9  -= bf2f(x1s[(w - 4) * 256 + c]);
        if (w + 7 <= 63) s13 += bf2f(x1s[(w + 7) * 256 + c]);
        if (w - 6 >= 0)  s13 -= bf2f(x1s[(w - 6) * 256 + c]);
    }
}

// ---------------------------------------------------------------------------
// P2: vertical (along h) pooling pass. block = (b, w, c-half). Writes
// y1,y2,y3,a1,a2,a3 into catT column sections 1..6.
// ---------------------------------------------------------------------------
__global__ __launch_bounds__(256) void pool_v(
    const unsigned short* __restrict__ pool, unsigned short* __restrict__ catT)
{
    int bid = blockIdx.x;              // 8*64*2 = 1024
    int chh = bid & 1, w = (bid >> 1) & 63, b = bid >> 7;
    int c0 = chh * 128;
    __shared__ __align__(16) unsigned short slab[6][64 * 128];
    const int tid = threadIdx.x, lane = tid & 63, wave = tid >> 6;
    for (int s6 = 0; s6 < 6; ++s6) {
        const unsigned short* src = pool + (long)s6 * 32768 * 256;
#pragma unroll
        for (int j = 0; j < 4; ++j) {
            int o = wave * 4096 + j * 1024 + lane * 16;
            int hh = o >> 8, ce = (o & 255) >> 1;
            GLL(src + ((long)b * 4096 + hh * 64 + w) * 256 + c0 + ce,
                (char*)slab[s6] + (wave * 4096 + j * 1024));
        }
    }
    __syncthreads();
    const int c = tid & 127, hg = tid >> 7;
    for (int hh = 0; hh < 32; ++hh) {
        int h = hg * 32 + hh;
        int lo2 = (h >= 2) ? h - 2 : 0, hi2 = (h <= 61) ? h + 2 : 63;
        int lo4 = (h >= 4) ? h - 4 : 0, hi4 = (h <= 59) ? h + 4 : 63;
        int lo6 = (h >= 6) ? h - 6 : 0, hi6 = (h <= 57) ? h + 6 : 63;
        float y1 = -1e30f, y2 = -1e30f, y3 = -1e30f;
        for (int d = lo2; d <= hi2; ++d) y1 = fmaxf(y1, bf2f(slab[0][d * 128 + c]));
        for (int d = lo4; d <= hi4; ++d) y2 = fmaxf(y2, bf2f(slab[1][d * 128 + c]));
        for (int d = lo6; d <= hi6; ++d) y3 = fmaxf(y3, bf2f(slab[2][d * 128 + c]));
        float s5 = 0.f, s9 = 0.f, s13 = 0.f;
        for (int d = lo2; d <= hi2; ++d) s5  += bf2f(slab[3][d * 128 + c]);
        for (int d = lo4; d <= hi4; ++d) s9  += bf2f(slab[4][d * 128 + c]);
        for (int d = lo6; d <= hi6; ++d) s13 += bf2f(slab[5][d * 128 + c]);
        long off = ((long)b * 4096 + h * 64 + w) * 1792 + c0 + c;
        catT[off + 256]  = f2bf(y1);
        catT[off + 512]  = f2bf(y2);
        catT[off + 768]  = f2bf(y3);
        catT[off + 1024] = f2bf(s13 * (1.f / 169.f));
        catT[off + 1280] = f2bf(s9  * (1.f / 81.f));
        catT[off + 1536] = f2bf(s5  * (1.f / 25.f));
    }
}

// ---------------------------------------------------------------------------
// S1: eH scores, block = (b, w).  eH[h,g] = sum_c q[h]*k[g] over column w,
// diag (g==h) masked.  -> attHlog (b,h,w,g) fp32
// ---------------------------------------------------------------------------
__global__ __launch_bounds__(256) void scores_h(
    const unsigned short* __restrict__ qk, float* __restrict__ attHlog)
{
    const int b = blockIdx.x >> 6, w = blockIdx.x & 63;
    __shared__ __align__(16) unsigned short Qs[64 * 232];
    __shared__ __align__(16) unsigned short Ks[64 * 232];
    const int tid = threadIdx.x, lane = tid & 63, wave = tid >> 6;
#pragma unroll
    for (int j = 0; j < 14; ++j) {
        int idx = tid + j * 256;          // 0..3583
        int s = idx >= 1792;
        int id2 = idx - s * 1792;
        int row = id2 / 28, cb = id2 - row * 28;
        bf16x8 v = *(const bf16x8*)(qk + ((long)b * 4096 + row * 64 + w) * 512 +
                                    s * 224 + cb * 8);
        *(bf16x8*)((s ? Ks : Qs) + row * 232 + cb * 8) = v;
    }
    __syncthreads();
    const int m0 = wave * 16, arow = lane & 15, kc = (lane >> 4) << 3;
    f32x4 acc[4] = {};
#pragma unroll
    for (int ks = 0; ks < 7; ++ks) {
        bf16x8 af = *(const bf16x8*)(Qs + (m0 + arow) * 232 + ks * 32 + kc);
#pragma unroll
        for (int nf = 0; nf < 4; ++nf) {
            bf16x8 bv = *(const bf16x8*)(Ks + (nf * 16 + arow) * 232 + ks * 32 + kc);
            acc[nf] = MFMA(af, bv, acc[nf]);
        }
    }
    const int rb = (lane >> 4) << 2;
#pragma unroll
    for (int nf = 0; nf < 4; ++nf) {
        int g = nf * 16 + arow;
#pragma unroll
        for (int r = 0; r < 4; ++r) {
            int h = m0 + rb + r;
            float v = acc[nf][r];
            if (g == h) v = -1e30f;
            attHlog[((long)(b * 64 + h) * 64 + w) * 64 + g] = v;
        }
    }
}

// ---------------------------------------------------------------------------
// S2: eW scores + fused softmax over concat([eH, eW], 128). block = (b, h).
// -> att (b,h,w,128) bf16, cols [0,64)=attH, [64,128)=attW
// ---------------------------------------------------------------------------
__global__ __launch_bounds__(256) void scores_w_softmax(
    const unsigned short* __restrict__ qk, const float* __restrict__ attHlog,
    unsigned short* __restrict__ att)
{
    const int b = blockIdx.x >> 6, h = blockIdx.x & 63;
    __shared__ __align__(16) unsigned short Qs[64 * 232];
    __shared__ __align__(16) unsigned short Ks[64 * 232];
    __shared__ float ews[64 * 65];
    const int tid = threadIdx.x, lane = tid & 63, wave = tid >> 6;
    const long nbase = (long)b * 4096 + h * 64;
#pragma unroll
    for (int j = 0; j < 14; ++j) {
        int idx = tid + j * 256;
        int s = idx >= 1792;
        int id2 = idx - s * 1792;
        int row = id2 / 28, cb = id2 - row * 28;
        bf16x8 v = *(const bf16x8*)(qk + (nbase + row) * 512 + s * 224 + cb * 8);
        *(bf16x8*)((s ? Ks : Qs) + row * 232 + cb * 8) = v;
    }
    __syncthreads();
    const int m0 = wave * 16, arow = lane & 15, kc = (lane >> 4) << 3;
    f32x4 acc[4] = {};
#pragma unroll
    for (int ks = 0; ks < 7; ++ks) {
        bf16x8 af = *(const bf16x8*)(Qs + (m0 + arow) * 232 + ks * 32 + kc);
#pragma unroll
        for (int nf = 0; nf < 4; ++nf) {
            bf16x8 bv = *(const bf16x8*)(Ks + (nf * 16 + arow) * 232 + ks * 32 + kc);
            acc[nf] = MFMA(af, bv, acc[nf]);
        }
    }
    const int rb = (lane >> 4) << 2;
#pragma unroll
    for (int nf = 0; nf < 4; ++nf)
#pragma unroll
        for (int r = 0; r < 4; ++r)
            ews[(m0 + rb + r) * 65 + nf * 16 + arow] = acc[nf][r];
    __syncthreads();
    // softmax: 4 threads per w-row, 32 entries each
    const int wl = tid >> 2, p = tid & 3;
    float eh[16], ew[16];
    const float* hrow = attHlog + ((long)(b * 64 + h) * 64 + wl) * 64 + p * 16;
#pragma unroll
    for (int j = 0; j < 16; ++j) eh[j] = hrow[j];
#pragma unroll
    for (int j = 0; j < 16; ++j) ew[j] = ews[wl * 65 + p * 16 + j];
    float mx = -1e30f;
#pragma unroll
    for (int j = 0; j < 16; ++j) { mx = fmaxf(mx, eh[j]); mx = fmaxf(mx, ew[j]); }
    mx = fmaxf(mx, __shfl_xor(mx, 1));
    mx = fmaxf(mx, __shfl_xor(mx, 2));
    float sm = 0.f;
#pragma unroll
    for (int j = 0; j < 16; ++j) {
        eh[j] = __expf(eh[j] - mx); sm += eh[j];
        ew[j] = __expf(ew[j] - mx); sm += ew[j];
    }
    sm += __shfl_xor(sm, 1);
    sm += __shfl_xor(sm, 2);
    float inv = 1.f / sm;
    unsigned short* orow = att + ((long)(b * 64 + h) * 64 + wl) * 128;
#pragma unroll
    for (int j = 0; j < 16; ++j) orow[p * 16 + j] = f2bf(eh[j] * inv);
#pragma unroll
    for (int j = 0; j < 16; ++j) orow[64 + p * 16 + j] = f2bf(ew[j] * inv);
}

// ---------------------------------------------------------------------------
// apply_att (per batch-pair bp): grid 512 = lb(2) x i(64) x chunk(4).
//   MODE 0: writes partial outH (part).   MODE 1: cat = gam*(outW+part)+cat.
// OUT[i2, c] = sum_g att[i2, g] * V[g, c],  M=64, N=448/chunk, K=64.
// ---------------------------------------------------------------------------
template <int MODE>
__global__ __launch_bounds__(256) void apply_att(
    const unsigned short* __restrict__ att, const unsigned short* __restrict__ vb,
    unsigned short* __restrict__ part, unsigned short* __restrict__ cat,
    const float* __restrict__ gamma, int bp)
{
    const int ch = blockIdx.x & 3;
    const int i  = (blockIdx.x >> 2) & 63;
    const int lb = blockIdx.x >> 8;
    const int b  = bp * 2 + lb;
    const int c0 = ch * 448;
    __shared__ __align__(16) unsigned short As[64 * 72];
    __shared__ __align__(16) unsigned short Vs[64 * 448];
    const int tid = threadIdx.x, lane = tid & 63, wave = tid >> 6;
    // stage attention slab (64 rows x 64 g), +8 pad per row
#pragma unroll
    for (int j = 0; j < 2; ++j) {
        int idx = tid + j * 256;
        int hh = idx >> 3, cb = idx & 7;
        long pos = (MODE == 0) ? ((long)(b * 64 + hh) * 64 + i)
                               : ((long)(b * 64 + i) * 64 + hh);
        bf16x8 v = *(const bf16x8*)(att + pos * 128 + MODE * 64 + cb * 8);
        *(bf16x8*)(As + hh * 72 + cb * 8) = v;
    }
    // stage V chunk [64 g][448 c] with 16B-chunk XOR swizzle on (g>>3)
#pragma unroll
    for (int j = 0; j < 14; ++j) {
        int idx = tid + j * 256;      // 0..3583
        int g = idx / 56, cb = idx - g * 56;
        long n = (MODE == 0) ? ((long)lb * 4096 + g * 64 + i)
                             : ((long)lb * 4096 + i * 64 + g);
        bf16x8 v = *(const bf16x8*)(vb + n * 1792 + c0 + cb * 8);
        int sw = (g >> 3) & 7;
        *(bf16x8*)(Vs + g * 448 + ((cb ^ sw) << 3)) = v;
    }
    __syncthreads();
    const int arow = lane & 15, kc8 = (lane >> 4) << 3;
    const int rb = (lane >> 4) << 2;
    f32x4 acc[4][7] = {};
#pragma unroll
    for (int ks = 0; ks < 2; ++ks) {
        const int k0 = ks * 32;
        bf16x8 af[4];
#pragma unroll
        for (int m = 0; m < 4; ++m)
            af[m] = *(const bf16x8*)(As + (m * 16 + arow) * 72 + k0 + kc8);
        const int g0 = k0 + kc8;
        const int sw = (g0 >> 3) & 7;
#pragma unroll
        for (int nf = 0; nf < 7; ++nf) {
            int cl = wave * 112 + nf * 16 + arow;
            int cb = cl >> 3, clo = cl & 7;
            const unsigned short* pp = Vs + g0 * 448 + ((cb ^ sw) << 3) + clo;
            bf16x8 bv;
#pragma unroll
            for (int j = 0; j < 8; ++j) bv[j] = (short)pp[j * 448];
#pragma unroll
            for (int m = 0; m < 4; ++m)
                acc[m][nf] = MFMA(af[m], bv, acc[m][nf]);
        }
    }
    const float gam = gamma[0];
#pragma unroll
    for (int nf = 0; nf < 7; ++nf) {
        const int c = c0 + wave * 112 + nf * 16 + arow;
#pragma unroll
        for (int m = 0; m < 4; ++m) {
#pragma unroll
            for (int r = 0; r < 4; ++r) {
                const int rl = m * 16 + rb + r;
                long n = (MODE == 0) ? ((long)lb * 4096 + rl * 64 + i)
                                     : ((long)lb * 4096 + i * 64 + rl);
                long idx2 = n * 1792 + c;
                if (MODE == 0) {
                    part[idx2] = f2bf(acc[m][nf][r]);
                } else {
                    float pv = bf2f(part[idx2]);
                    float cv = bf2f(cat[idx2]);
                    cat[idx2] = f2bf(gam * (acc[m][nf][r] + pv) + cv);
                }
            }
        }
    }
}

// ---------------------------------------------------------------------------
// launcher
// ---------------------------------------------------------------------------
extern "C" void kernel_launch(void* const* d_in, const int* in_sizes, int n_in,
                              void* d_out, int out_size, void* d_ws, size_t ws_size,
                              hipStream_t stream)
{
    const float* x     = (const float*)d_in[0];
    const float* cv1_w = (const float*)d_in[1];
    const float* cv1_g = (const float*)d_in[2];
    const float* cv1_b = (const float*)d_in[3];
    const float* cv1_m = (const float*)d_in[4];
    const float* cv1_v = (const float*)d_in[5];
    const float* q_w   = (const float*)d_in[6];
    const float* q_b   = (const float*)d_in[7];
    const float* k_w   = (const float*)d_in[8];
    const float* k_b   = (const float*)d_in[9];
    const float* v_w   = (const float*)d_in[10];
    const float* v_b   = (const float*)d_in[11];
    const float* gamma = (const float*)d_in[12];
    const float* cv2_w = (const float*)d_in[13];
    const float* cv2_g = (const float*)d_in[14];
    const float* cv2_b = (const float*)d_in[15];
    const float* cv2_m = (const float*)d_in[16];
    const float* cv2_v = (const float*)d_in[17];

    char* ws = (char*)d_ws;
    // ---- workspace map (total 229,638,144 B = 219 MiB) ----
    unsigned short* wb1  = (unsigned short*)(ws + 0);          //  256x512
    unsigned short* wqk  = (unsigned short*)(ws + 262144);     //  512x1792
    unsigned short* wv   = (unsigned short*)(ws + 2097152);    // 1792x1792
    unsigned short* wc2  = (unsigned short*)(ws + 8519680);    //  512x1792
    float* sc1           = (float*)(ws + 10354688);
    float* sh1           = (float*)(ws + 10358784);
    float* sc2           = (float*)(ws + 10362880);
    float* sh2           = (float*)(ws + 10366976);
    float* qkb           = (float*)(ws + 10371072);
    unsigned short* catT = (unsigned short*)(ws + 11534336);   // 32768x1792, live to end
    const long C_OFF = 128974848;                              // 96 MiB time-shared region
    unsigned short* xT    = (unsigned short*)(ws + C_OFF);           // ph1: 32 MiB
    unsigned short* poolb = (unsigned short*)(ws + C_OFF);           // ph2: 96 MiB
    float* attHlog        = (float*)(ws + C_OFF);                    // ph3: 8 MiB
    unsigned short* attb  = (unsigned short*)(ws + C_OFF + 8388608); // ph3: 8 MiB
    unsigned short* vbuf2 = (unsigned short*)(ws + C_OFF + 16777216);// ph3: 28 MiB/pair
    unsigned short* part2 = (unsigned short*)(ws + C_OFF + 46137344);// ph3: 28 MiB/pair
    float* cv2tmp         = (float*)(ws + C_OFF + 16777216);         // ph4: 64 MiB
    unsigned short* qk    = (unsigned short*)d_out;                  // 32 MiB scratch in d_out

    prep_kernel<<<2048, 256, 0, stream>>>(
        cv1_w, cv1_g, cv1_b, cv1_m, cv1_v, q_w, q_b, k_w, k_b, v_w,
        cv2_w, cv2_g, cv2_b, cv2_m, cv2_v,
        wb1, wqk, wv, wc2, sc1, sh1, sc2, sh2, qkb);

    transpose_x<<<4096, 256, 0, stream>>>(x, xT);

    // cv1: x1 = silu(bn(W1 . x)) -> catT cols [0,256)
    gemm_nt<0><<<dim3(256, 2), 256, 0, stream>>>(xT, 512, wb1, 512, 512,
                                                 catT, 1792, sc1, sh1);

    pool_h<<<512, 256, 0, stream>>>(catT, poolb);
    pool_v<<<1024, 256, 0, stream>>>(poolb, catT);

    // q,k (stacked, padded to 512 cols) -> qk (in d_out)
    gemm_nt<1><<<dim3(256, 4), 256, 0, stream>>>(catT, 1792, wqk, 1792, 1792,
                                                 qk, 512, qkb, nullptr);

    scores_h<<<512, 256, 0, stream>>>(qk, attHlog);
    scores_w_softmax<<<512, 256, 0, stream>>>(qk, attHlog, attb);

    // per batch-pair: v GEMM + criss-cross apply (result in-place into catT)
    for (int bp = 0; bp < 4; ++bp) {
        const unsigned short* Ap = catT + (long)bp * 8192 * 1792;
        unsigned short* catp     = catT + (long)bp * 8192 * 1792;
        gemm_nt<1><<<dim3(64, 14), 256, 0, stream>>>(Ap, 1792, wv, 1792, 1792,
                                                     vbuf2, 1792, v_b, nullptr);
        apply_att<0><<<512, 256, 0, stream>>>(attb, vbuf2, part2, catp, gamma, bp);
        apply_att<1><<<512, 256, 0, stream>>>(attb, vbuf2, part2, catp, gamma, bp);
    }

    // cv2: silu(bn(W2 . att)) -> fp32 tmp, then transpose to NCHW
    gemm_nt<2><<<dim3(256, 4), 256, 0, stream>>>(catT, 1792, wc2, 1792, 1792,
                                                 cv2tmp, 512, sc2, sh2);
    transpose_out<<<4096, 256, 0, stream>>>(cv2tmp, (float*)d_out);
}

// Round 3
// 937.970 us; speedup vs baseline: 1.3196x; 1.3196x over previous
//
#include <hip/hip_runtime.h>

// ---------------------------------------------------------------------------
// SPPF + criss-cross attention, MI355X bf16-MFMA pipeline.
// Layout convention: "position-major" activations  (B*H*W, C) row-major.
// Workspace budget: 229,638,144 bytes (219 MiB). qk lives in d_out (scratch
// until the final transpose overwrites it).
// Pool planes are stored W-MAJOR (b, w, h, c) so the vertical pass reads
// contiguous slabs.
// ---------------------------------------------------------------------------

typedef short bf16x8 __attribute__((ext_vector_type(8)));
typedef float f32x4  __attribute__((ext_vector_type(4)));

#define DEV __device__ __forceinline__

DEV float bf2f(unsigned short u) {
    unsigned int i = ((unsigned int)u) << 16;
    float f; __builtin_memcpy(&f, &i, 4); return f;
}
DEV unsigned short f2bf(float f) {
    unsigned int i; __builtin_memcpy(&i, &f, 4);
    unsigned int r = i + 0x7FFFu + ((i >> 16) & 1u);
    return (unsigned short)(r >> 16);
}
DEV float fsilu(float v) { return v / (1.f + __expf(-v)); }

// global -> LDS async copy, 16B per lane. LDS base must be wave-uniform.
#define GLL(gsrc, ldst)                                                        \
    __builtin_amdgcn_global_load_lds(                                          \
        (const __attribute__((address_space(1))) unsigned int*)(gsrc),         \
        (__attribute__((address_space(3))) unsigned int*)(ldst), 16, 0, 0)

#define MFMA(a, b, c) __builtin_amdgcn_mfma_f32_16x16x32_bf16((a), (b), (c), 0, 0, 0)

// ---------------------------------------------------------------------------
// prep: fp32 weights -> bf16, stacked/padded qk weights, BN scale/shift vecs
// ---------------------------------------------------------------------------
__global__ __launch_bounds__(256) void prep_kernel(
    const float* __restrict__ cv1_w, const float* __restrict__ cv1_g,
    const float* __restrict__ cv1_b, const float* __restrict__ cv1_m,
    const float* __restrict__ cv1_v,
    const float* __restrict__ q_w, const float* __restrict__ q_b,
    const float* __restrict__ k_w, const float* __restrict__ k_b,
    const float* __restrict__ v_w,
    const float* __restrict__ cv2_w, const float* __restrict__ cv2_g,
    const float* __restrict__ cv2_b, const float* __restrict__ cv2_m,
    const float* __restrict__ cv2_v,
    unsigned short* __restrict__ wb1, unsigned short* __restrict__ wqk,
    unsigned short* __restrict__ wv, unsigned short* __restrict__ wc2,
    float* __restrict__ sc1, float* __restrict__ sh1,
    float* __restrict__ sc2, float* __restrict__ sh2,
    float* __restrict__ qkb)
{
    for (int i = blockIdx.x * 256 + threadIdx.x; i < 3211264;
         i += gridDim.x * 256) {
        wv[i] = f2bf(v_w[i]);
        if (i < 917504) {
            wc2[i] = f2bf(cv2_w[i]);
            int row = i / 1792;
            int col = i - row * 1792;
            float qv = (row < 224) ? q_w[i]
                       : (row < 448) ? k_w[(row - 224) * 1792 + col] : 0.f;
            wqk[i] = f2bf(qv);
        }
        if (i < 131072) wb1[i] = f2bf(cv1_w[i]);
        if (i < 512) {
            qkb[i] = (i < 224) ? q_b[i] : (i < 448 ? k_b[i - 224] : 0.f);
            float sc = cv2_g[i] * rsqrtf(cv2_v[i] + 1e-5f);
            sc2[i] = sc; sh2[i] = cv2_b[i] - cv2_m[i] * sc;
        }
        if (i < 256) {
            float sc = cv1_g[i] * rsqrtf(cv1_v[i] + 1e-5f);
            sc1[i] = sc; sh1[i] = cv1_b[i] - cv1_m[i] * sc;
        }
    }
}

// ---------------------------------------------------------------------------
// transpose x (8,512,4096) fp32  ->  xT (32768, 512) bf16
// ---------------------------------------------------------------------------
__global__ __launch_bounds__(256) void transpose_x(
    const float* __restrict__ x, unsigned short* __restrict__ xT)
{
    int bid = blockIdx.x;               // 8 * 8 * 64 = 4096 blocks
    int nt = bid & 63, ct = (bid >> 6) & 7, b = bid >> 9;
    __shared__ float tile[64][65];
    int tid = threadIdx.x;
    int n0 = nt * 64, c0 = ct * 64;
#pragma unroll
    for (int it = 0; it < 16; ++it) {
        int idx = tid + it * 256;
        int r = idx >> 6, cc = idx & 63;          // r = c-local, cc = n-local
        tile[r][cc] = x[((long)(b * 512 + c0 + r)) * 4096 + n0 + cc];
    }
    __syncthreads();
#pragma unroll
    for (int it = 0; it < 16; ++it) {
        int idx = tid + it * 256;
        int r = idx >> 6, cc = idx & 63;          // r = n-local, cc = c-local
        xT[((long)(b * 4096 + n0 + r)) * 512 + c0 + cc] = f2bf(tile[cc][r]);
    }
}

// ---------------------------------------------------------------------------
// transpose cv2tmp (32768,512) fp32 -> d_out (8,512,4096) fp32
// ---------------------------------------------------------------------------
__global__ __launch_bounds__(256) void transpose_out(
    const float* __restrict__ t, float* __restrict__ outp)
{
    int bid = blockIdx.x;               // 8 * 8 * 64 = 4096 blocks
    int nt = bid & 63, ot = (bid >> 6) & 7, b = bid >> 9;
    __shared__ float tile[64][65];
    int tid = threadIdx.x;
    int n0 = nt * 64, o0 = ot * 64;
#pragma unroll
    for (int it = 0; it < 16; ++it) {
        int idx = tid + it * 256;
        int r = idx >> 6, cc = idx & 63;          // r = n-local, cc = o-local
        tile[r][cc] = t[((long)(b * 4096 + n0 + r)) * 512 + o0 + cc];
    }
    __syncthreads();
#pragma unroll
    for (int it = 0; it < 16; ++it) {
        int idx = tid + it * 256;
        int r = idx >> 6, cc = idx & 63;          // r = o-local, cc = n-local
        outp[((long)(b * 512 + o0 + r)) * 4096 + n0 + cc] = tile[cc][r];
    }
}

// ---------------------------------------------------------------------------
// NT GEMM, m97-style 128x128 tile, BK=32, 4 waves (2x2), 16x16x32 bf16 MFMA.
// C[m,n] = sum_k A[m,k]*B[n,k].  A = activations (M=positions), B = weights.
// EPI: 0 = BN+SiLU -> bf16, 1 = +bias -> bf16, 2 = BN+SiLU -> fp32
// ---------------------------------------------------------------------------
template <int EPI>
__global__ __launch_bounds__(256) void gemm_nt(
    const unsigned short* __restrict__ A, int lda,
    const unsigned short* __restrict__ B, int ldb,
    int K, void* __restrict__ outp, int ldo,
    const float* __restrict__ p0, const float* __restrict__ p1)
{
    __shared__ __align__(16) unsigned short Ash[128 * 32];
    __shared__ __align__(16) unsigned short Bsh[128 * 32];
    const int tid = threadIdx.x;
    const int lane = tid & 63, wave = tid >> 6;
    const int wm = wave & 1, wn = wave >> 1;
    const long tile_m = (long)blockIdx.x * 128;
    const int tile_n = blockIdx.y * 128;
    f32x4 acc[4][4] = {};
    const int nsteps = K >> 5;
    // staging geometry: wave w stages bytes [w*2048, w*2048+2048) of each tile
    const int o0 = wave * 2048 + lane * 16;
    const int r0 = o0 >> 6, kk0 = (o0 & 63) >> 1;
    const int o1 = o0 + 1024;
    const int r1 = o1 >> 6, kk1 = (o1 & 63) >> 1;
    const unsigned short* Ab0 = A + (tile_m + r0) * (long)lda + kk0;
    const unsigned short* Ab1 = A + (tile_m + r1) * (long)lda + kk1;
    const unsigned short* Bb0 = B + (long)(tile_n + r0) * ldb + kk0;
    const unsigned short* Bb1 = B + (long)(tile_n + r1) * ldb + kk1;
    unsigned short* Ad0 = Ash + wave * 1024;
    unsigned short* Ad1 = Ash + wave * 1024 + 512;
    unsigned short* Bd0 = Bsh + wave * 1024;
    unsigned short* Bd1 = Bsh + wave * 1024 + 512;
    const int arow = lane & 15;
    const int kcol = (lane >> 4) << 3;
    for (int kt = 0; kt < nsteps; ++kt) {
        __syncthreads();
        const int ke = kt << 5;
        GLL(Ab0 + ke, Ad0);
        GLL(Ab1 + ke, Ad1);
        GLL(Bb0 + ke, Bd0);
        GLL(Bb1 + ke, Bd1);
        __syncthreads();
        bf16x8 af[4], bfv[4];
#pragma unroll
        for (int m = 0; m < 4; ++m)
            af[m] = *(const bf16x8*)(Ash + (wm * 64 + m * 16 + arow) * 32 + kcol);
#pragma unroll
        for (int n = 0; n < 4; ++n)
            bfv[n] = *(const bf16x8*)(Bsh + (wn * 64 + n * 16 + arow) * 32 + kcol);
#pragma unroll
        for (int m = 0; m < 4; ++m)
#pragma unroll
            for (int n = 0; n < 4; ++n)
                acc[m][n] = MFMA(af[m], bfv[n], acc[m][n]);
    }
    // epilogue
    const int rbase = (lane >> 4) << 2;
    const int cbase = lane & 15;
#pragma unroll
    for (int n = 0; n < 4; ++n) {
        const int gcol = tile_n + wn * 64 + n * 16 + cbase;
        const float s0 = p0[gcol];
        const float s1 = (EPI != 1) ? p1[gcol] : 0.f;
#pragma unroll
        for (int m = 0; m < 4; ++m) {
#pragma unroll
            for (int r = 0; r < 4; ++r) {
                const long grow = tile_m + wm * 64 + m * 16 + rbase + r;
                float v = acc[m][n][r];
                if (EPI != 1) { v = v * s0 + s1; v = fsilu(v); }
                else          { v += s0; }
                if (EPI == 2) ((float*)outp)[grow * ldo + gcol] = v;
                else ((unsigned short*)outp)[grow * ldo + gcol] = f2bf(v);
            }
        }
    }
}

// ---------------------------------------------------------------------------
// P1: horizontal (along w) pooling pass. block = (b,h). Produces row-pass
// rmax5/rmax9/rmax13, rsum5/rsum9/rsum13 into 6 pool planes, stored W-MAJOR:
// plane[(b*4096 + w*64 + h)*256 + c]  (so P2 reads contiguous slabs).
// ---------------------------------------------------------------------------
__global__ __launch_bounds__(256) void pool_h(
    const unsigned short* __restrict__ catT, unsigned short* __restrict__ pool)
{
    const int b = blockIdx.x >> 6, h = blockIdx.x & 63;
    __shared__ __align__(16) unsigned short x1s[64 * 256];
    __shared__ __align__(16) unsigned short rm5[64 * 256];
    const int tid = threadIdx.x, lane = tid & 63, wave = tid >> 6;
    const long nb = (long)b * 4096 + h * 64;
    // stage x1 slab (x1 = catT cols [0,256))
#pragma unroll
    for (int j = 0; j < 8; ++j) {
        int o = wave * 8192 + j * 1024 + lane * 16;   // byte offset in slab
        int w = o >> 9, c = (o & 511) >> 1;
        GLL(catT + (nb + w) * 1792 + c,
            (char*)x1s + (wave * 8192 + j * 1024));
    }
    __syncthreads();
    const int c = tid;   // one channel per thread; column-private below
    for (int w = 0; w < 64; ++w) {
        int lo = (w >= 2) ? w - 2 : 0, hi = (w <= 61) ? w + 2 : 63;
        float m = bf2f(x1s[lo * 256 + c]);
        for (int d = lo + 1; d <= hi; ++d) m = fmaxf(m, bf2f(x1s[d * 256 + c]));
        rm5[w * 256 + c] = f2bf(m);
    }
    float s5 = 0.f, s9 = 0.f, s13 = 0.f;
#pragma unroll
    for (int d = 0; d <= 2; ++d) s5  += bf2f(x1s[d * 256 + c]);
#pragma unroll
    for (int d = 0; d <= 4; ++d) s9  += bf2f(x1s[d * 256 + c]);
#pragma unroll
    for (int d = 0; d <= 6; ++d) s13 += bf2f(x1s[d * 256 + c]);
    unsigned short* q0 = pool;
    unsigned short* q1 = pool + (long)32768 * 256;
    unsigned short* q2 = pool + (long)32768 * 512;
    unsigned short* q3 = pool + (long)32768 * 768;
    unsigned short* q4 = pool + (long)32768 * 1024;
    unsigned short* q5 = pool + (long)32768 * 1280;
    const long wb = (long)b * 4096 + h;          // w-major dest base
    for (int w = 0; w < 64; ++w) {
        long off = (wb + (long)w * 64) * 256 + c;
        float v5 = bf2f(rm5[w * 256 + c]);
        int wm2 = (w >= 2) ? w - 2 : 0, wp2 = (w <= 61) ? w + 2 : 63;
        int wm4 = (w >= 4) ? w - 4 : 0, wp4 = (w <= 59) ? w + 4 : 63;
        float v9  = fmaxf(bf2f(rm5[wm2 * 256 + c]), bf2f(rm5[wp2 * 256 + c]));
        float v13 = fmaxf(v5, fmaxf(bf2f(rm5[wm4 * 256 + c]),
                                    bf2f(rm5[wp4 * 256 + c])));
        q0[off] = f2bf(v5);  q1[off] = f2bf(v9);  q2[off] = f2bf(v13);
        q3[off] = f2bf(s5);  q4[off] = f2bf(s9);  q5[off] = f2bf(s13);
        // advance clamped windows to w+1
        if (w + 3 <= 63) s5  += bf2f(x1s[(w + 3) * 256 + c]);
        if (w - 2 >= 0)  s5  -= bf2f(x1s[(w - 2) * 256 + c]);
        if (w + 5 <= 63) s9  += bf2f(x1s[(w + 5) * 256 + c]);
        if (w - 4 >= 0)  s9  -= bf2f(x1s[(w - 4) * 256 + c]);
        if (w + 7 <= 63) s13 += bf2f(x1s[(w + 7) * 256 + c]);
        if (w - 6 >= 0)  s13 -= bf2f(x1s[(w - 6) * 256 + c]);
    }
}

// ---------------------------------------------------------------------------
// P2: vertical (along h) pass. grid (1024, 6): x = (b, w, c-half), y = section.
// Each block stages ONE 64h x 128c slab (16 KB LDS) of its plane and writes
// one catT column section. Max sections: direct clamped window; sum sections:
// incremental sliding window.
// ---------------------------------------------------------------------------
__global__ __launch_bounds__(256) void pool_v(
    const unsigned short* __restrict__ pool, unsigned short* __restrict__ catT)
{
    const int s6 = blockIdx.y;
    const int bid = blockIdx.x;        // 8*64*2 = 1024
    const int chh = bid & 1, w = (bid >> 1) & 63, b = bid >> 7;
    const int c0 = chh * 128;
    __shared__ __align__(16) unsigned short slab[64 * 128];
    const int tid = threadIdx.x, lane = tid & 63, wave = tid >> 6;
    const unsigned short* src = pool + (long)s6 * 32768 * 256 +
                                ((long)b * 4096 + (long)w * 64) * 256 + c0;
#pragma unroll
    for (int j = 0; j < 4; ++j) {
        int o = j * 4096 + wave * 1024 + lane * 16;   // byte offset in slab
        int hh = o >> 8, ce = (o & 255) >> 1;
        GLL(src + hh * 256 + ce, (char*)slab + (j * 4096 + wave * 1024));
    }
    __syncthreads();
    const int c = tid & 127, hg = tid >> 7;
    const int rr[6]   = {2, 4, 6, 2, 4, 6};
    const int dsec[6] = {256, 512, 768, 1536, 1280, 1024};
    const float scl[6] = {0.f, 0.f, 0.f, 1.f / 25.f, 1.f / 81.f, 1.f / 169.f};
    const int r = rr[s6];
    const long dbase = ((long)b * 4096 + w) * 1792 + dsec[s6] + c0 + c;
    const int h0 = hg * 32;
    if (s6 < 3) {
        for (int hh = 0; hh < 32; ++hh) {
            int h = h0 + hh;
            int lo = (h - r >= 0) ? h - r : 0, hi = (h + r <= 63) ? h + r : 63;
            float m = bf2f(slab[lo * 128 + c]);
            for (int d = lo + 1; d <= hi; ++d)
                m = fmaxf(m, bf2f(slab[d * 128 + c]));
            catT[dbase + (long)h * (64 * 1792)] = f2bf(m);
        }
    } else {
        float s = 0.f;
        int lo0 = (h0 - r >= 0) ? h0 - r : 0, hi0 = (h0 + r <= 63) ? h0 + r : 63;
        for (int d = lo0; d <= hi0; ++d) s += bf2f(slab[d * 128 + c]);
        const float sc = scl[s6];
        for (int hh = 0; hh < 32; ++hh) {
            int h = h0 + hh;
            catT[dbase + (long)h * (64 * 1792)] = f2bf(s * sc);
            if (h + 1 + r <= 63) s += bf2f(slab[(h + 1 + r) * 128 + c]);
            if (h - r >= 0)      s -= bf2f(slab[(h - r) * 128 + c]);
        }
    }
}

// ---------------------------------------------------------------------------
// S1: eH scores, block = (b, w).  eH[h,g] = sum_c q[h]*k[g] over column w,
// diag (g==h) masked.  -> attHlog (b,h,w,g) fp32
// ---------------------------------------------------------------------------
__global__ __launch_bounds__(256) void scores_h(
    const unsigned short* __restrict__ qk, float* __restrict__ attHlog)
{
    const int b = blockIdx.x >> 6, w = blockIdx.x & 63;
    __shared__ __align__(16) unsigned short Qs[64 * 232];
    __shared__ __align__(16) unsigned short Ks[64 * 232];
    const int tid = threadIdx.x, lane = tid & 63, wave = tid >> 6;
#pragma unroll
    for (int j = 0; j < 14; ++j) {
        int idx = tid + j * 256;          // 0..3583
        int s = idx >= 1792;
        int id2 = idx - s * 1792;
        int row = id2 / 28, cb = id2 - row * 28;
        bf16x8 v = *(const bf16x8*)(qk + ((long)b * 4096 + row * 64 + w) * 512 +
                                    s * 224 + cb * 8);
        *(bf16x8*)((s ? Ks : Qs) + row * 232 + cb * 8) = v;
    }
    __syncthreads();
    const int m0 = wave * 16, arow = lane & 15, kc = (lane >> 4) << 3;
    f32x4 acc[4] = {};
#pragma unroll
    for (int ks = 0; ks < 7; ++ks) {
        bf16x8 af = *(const bf16x8*)(Qs + (m0 + arow) * 232 + ks * 32 + kc);
#pragma unroll
        for (int nf = 0; nf < 4; ++nf) {
            bf16x8 bv = *(const bf16x8*)(Ks + (nf * 16 + arow) * 232 + ks * 32 + kc);
            acc[nf] = MFMA(af, bv, acc[nf]);
        }
    }
    const int rb = (lane >> 4) << 2;
#pragma unroll
    for (int nf = 0; nf < 4; ++nf) {
        int g = nf * 16 + arow;
#pragma unroll
        for (int r = 0; r < 4; ++r) {
            int h = m0 + rb + r;
            float v = acc[nf][r];
            if (g == h) v = -1e30f;
            attHlog[((long)(b * 64 + h) * 64 + w) * 64 + g] = v;
        }
    }
}

// ---------------------------------------------------------------------------
// S2: eW scores + fused softmax over concat([eH, eW], 128). block = (b, h).
// -> att (b,h,w,128) bf16, cols [0,64)=attH, [64,128)=attW
// ---------------------------------------------------------------------------
__global__ __launch_bounds__(256) void scores_w_softmax(
    const unsigned short* __restrict__ qk, const float* __restrict__ attHlog,
    unsigned short* __restrict__ att)
{
    const int b = blockIdx.x >> 6, h = blockIdx.x & 63;
    __shared__ __align__(16) unsigned short Qs[64 * 232];
    __shared__ __align__(16) unsigned short Ks[64 * 232];
    __shared__ float ews[64 * 65];
    const int tid = threadIdx.x, lane = tid & 63, wave = tid >> 6;
    const long nbase = (long)b * 4096 + h * 64;
#pragma unroll
    for (int j = 0; j < 14; ++j) {
        int idx = tid + j * 256;
        int s = idx >= 1792;
        int id2 = idx - s * 1792;
        int row = id2 / 28, cb = id2 - row * 28;
        bf16x8 v = *(const bf16x8*)(qk + (nbase + row) * 512 + s * 224 + cb * 8);
        *(bf16x8*)((s ? Ks : Qs) + row * 232 + cb * 8) = v;
    }
    __syncthreads();
    const int m0 = wave * 16, arow = lane & 15, kc = (lane >> 4) << 3;
    f32x4 acc[4] = {};
#pragma unroll
    for (int ks = 0; ks < 7; ++ks) {
        bf16x8 af = *(const bf16x8*)(Qs + (m0 + arow) * 232 + ks * 32 + kc);
#pragma unroll
        for (int nf = 0; nf < 4; ++nf) {
            bf16x8 bv = *(const bf16x8*)(Ks + (nf * 16 + arow) * 232 + ks * 32 + kc);
            acc[nf] = MFMA(af, bv, acc[nf]);
        }
    }
    const int rb = (lane >> 4) << 2;
#pragma unroll
    for (int nf = 0; nf < 4; ++nf)
#pragma unroll
        for (int r = 0; r < 4; ++r)
            ews[(m0 + rb + r) * 65 + nf * 16 + arow] = acc[nf][r];
    __syncthreads();
    // softmax: 4 threads per w-row, 32 entries each
    const int wl = tid >> 2, p = tid & 3;
    float eh[16], ew[16];
    const float* hrow = attHlog + ((long)(b * 64 + h) * 64 + wl) * 64 + p * 16;
#pragma unroll
    for (int j = 0; j < 16; ++j) eh[j] = hrow[j];
#pragma unroll
    for (int j = 0; j < 16; ++j) ew[j] = ews[wl * 65 + p * 16 + j];
    float mx = -1e30f;
#pragma unroll
    for (int j = 0; j < 16; ++j) { mx = fmaxf(mx, eh[j]); mx = fmaxf(mx, ew[j]); }
    mx = fmaxf(mx, __shfl_xor(mx, 1));
    mx = fmaxf(mx, __shfl_xor(mx, 2));
    float sm = 0.f;
#pragma unroll
    for (int j = 0; j < 16; ++j) {
        eh[j] = __expf(eh[j] - mx); sm += eh[j];
        ew[j] = __expf(ew[j] - mx); sm += ew[j];
    }
    sm += __shfl_xor(sm, 1);
    sm += __shfl_xor(sm, 2);
    float inv = 1.f / sm;
    unsigned short* orow = att + ((long)(b * 64 + h) * 64 + wl) * 128;
#pragma unroll
    for (int j = 0; j < 16; ++j) orow[p * 16 + j] = f2bf(eh[j] * inv);
#pragma unroll
    for (int j = 0; j < 16; ++j) orow[64 + p * 16 + j] = f2bf(ew[j] * inv);
}

// ---------------------------------------------------------------------------
// apply_att (per batch-pair bp): grid 512 = lb(2) x i(64) x chunk(4).
//   MODE 0: writes partial outH (part).   MODE 1: cat = gam*(outW+part)+cat.
// OUT[i2, c] = sum_g att[i2, g] * V[g, c],  M=64, N=448/chunk, K=64.
// ---------------------------------------------------------------------------
template <int MODE>
__global__ __launch_bounds__(256) void apply_att(
    const unsigned short* __restrict__ att, const unsigned short* __restrict__ vb,
    unsigned short* __restrict__ part, unsigned short* __restrict__ cat,
    const float* __restrict__ gamma, int bp)
{
    const int ch = blockIdx.x & 3;
    const int i  = (blockIdx.x >> 2) & 63;
    const int lb = blockIdx.x >> 8;
    const int b  = bp * 2 + lb;
    const int c0 = ch * 448;
    __shared__ __align__(16) unsigned short As[64 * 72];
    __shared__ __align__(16) unsigned short Vs[64 * 448];
    const int tid = threadIdx.x, lane = tid & 63, wave = tid >> 6;
    // stage attention slab (64 rows x 64 g), +8 pad per row
#pragma unroll
    for (int j = 0; j < 2; ++j) {
        int idx = tid + j * 256;
        int hh = idx >> 3, cb = idx & 7;
        long pos = (MODE == 0) ? ((long)(b * 64 + hh) * 64 + i)
                               : ((long)(b * 64 + i) * 64 + hh);
        bf16x8 v = *(const bf16x8*)(att + pos * 128 + MODE * 64 + cb * 8);
        *(bf16x8*)(As + hh * 72 + cb * 8) = v;
    }
    // stage V chunk [64 g][448 c] with 16B-chunk XOR swizzle on (g>>3)
#pragma unroll
    for (int j = 0; j < 14; ++j) {
        int idx = tid + j * 256;      // 0..3583
        int g = idx / 56, cb = idx - g * 56;
        long n = (MODE == 0) ? ((long)lb * 4096 + g * 64 + i)
                             : ((long)lb * 4096 + i * 64 + g);
        bf16x8 v = *(const bf16x8*)(vb + n * 1792 + c0 + cb * 8);
        int sw = (g >> 3) & 7;
        *(bf16x8*)(Vs + g * 448 + ((cb ^ sw) << 3)) = v;
    }
    __syncthreads();
    const int arow = lane & 15, kc8 = (lane >> 4) << 3;
    const int rb = (lane >> 4) << 2;
    f32x4 acc[4][7] = {};
#pragma unroll
    for (int ks = 0; ks < 2; ++ks) {
        const int k0 = ks * 32;
        bf16x8 af[4];
#pragma unroll
        for (int m = 0; m < 4; ++m)
            af[m] = *(const bf16x8*)(As + (m * 16 + arow) * 72 + k0 + kc8);
        const int g0 = k0 + kc8;
        const int sw = (g0 >> 3) & 7;
#pragma unroll
        for (int nf = 0; nf < 7; ++nf) {
            int cl = wave * 112 + nf * 16 + arow;
            int cb = cl >> 3, clo = cl & 7;
            const unsigned short* pp = Vs + g0 * 448 + ((cb ^ sw) << 3) + clo;
            bf16x8 bv;
#pragma unroll
            for (int j = 0; j < 8; ++j) bv[j] = (short)pp[j * 448];
#pragma unroll
            for (int m = 0; m < 4; ++m)
                acc[m][nf] = MFMA(af[m], bv, acc[m][nf]);
        }
    }
    const float gam = gamma[0];
#pragma unroll
    for (int nf = 0; nf < 7; ++nf) {
        const int c = c0 + wave * 112 + nf * 16 + arow;
#pragma unroll
        for (int m = 0; m < 4; ++m) {
#pragma unroll
            for (int r = 0; r < 4; ++r) {
                const int rl = m * 16 + rb + r;
                long n = (MODE == 0) ? ((long)lb * 4096 + rl * 64 + i)
                                     : ((long)lb * 4096 + i * 64 + rl);
                long idx2 = n * 1792 + c;
                if (MODE == 0) {
                    part[idx2] = f2bf(acc[m][nf][r]);
                } else {
                    float pv = bf2f(part[idx2]);
                    float cv = bf2f(cat[idx2]);
                    cat[idx2] = f2bf(gam * (acc[m][nf][r] + pv) + cv);
                }
            }
        }
    }
}

// ---------------------------------------------------------------------------
// launcher
// ---------------------------------------------------------------------------
extern "C" void kernel_launch(void* const* d_in, const int* in_sizes, int n_in,
                              void* d_out, int out_size, void* d_ws, size_t ws_size,
                              hipStream_t stream)
{
    const float* x     = (const float*)d_in[0];
    const float* cv1_w = (const float*)d_in[1];
    const float* cv1_g = (const float*)d_in[2];
    const float* cv1_b = (const float*)d_in[3];
    const float* cv1_m = (const float*)d_in[4];
    const float* cv1_v = (const float*)d_in[5];
    const float* q_w   = (const float*)d_in[6];
    const float* q_b   = (const float*)d_in[7];
    const float* k_w   = (const float*)d_in[8];
    const float* k_b   = (const float*)d_in[9];
    const float* v_w   = (const float*)d_in[10];
    const float* v_b   = (const float*)d_in[11];
    const float* gamma = (const float*)d_in[12];
    const float* cv2_w = (const float*)d_in[13];
    const float* cv2_g = (const float*)d_in[14];
    const float* cv2_b = (const float*)d_in[15];
    const float* cv2_m = (const float*)d_in[16];
    const float* cv2_v = (const float*)d_in[17];

    char* ws = (char*)d_ws;
    // ---- workspace map (total 229,638,144 B = 219 MiB) ----
    unsigned short* wb1  = (unsigned short*)(ws + 0);          //  256x512
    unsigned short* wqk  = (unsigned short*)(ws + 262144);     //  512x1792
    unsigned short* wv   = (unsigned short*)(ws + 2097152);    // 1792x1792
    unsigned short* wc2  = (unsigned short*)(ws + 8519680);    //  512x1792
    float* sc1           = (float*)(ws + 10354688);
    float* sh1           = (float*)(ws + 10358784);
    float* sc2           = (float*)(ws + 10362880);
    float* sh2           = (float*)(ws + 10366976);
    float* qkb           = (float*)(ws + 10371072);
    unsigned short* catT = (unsigned short*)(ws + 11534336);   // 32768x1792, live to end
    const long C_OFF = 128974848;                              // 96 MiB time-shared region
    unsigned short* xT    = (unsigned short*)(ws + C_OFF);           // ph1: 32 MiB
    unsigned short* poolb = (unsigned short*)(ws + C_OFF);           // ph2: 96 MiB
    float* attHlog        = (float*)(ws + C_OFF);                    // ph3: 8 MiB
    unsigned short* attb  = (unsigned short*)(ws + C_OFF + 8388608); // ph3: 8 MiB
    unsigned short* vbuf2 = (unsigned short*)(ws + C_OFF + 16777216);// ph3: 28 MiB/pair
    unsigned short* part2 = (unsigned short*)(ws + C_OFF + 46137344);// ph3: 28 MiB/pair
    float* cv2tmp         = (float*)(ws + C_OFF + 16777216);         // ph4: 64 MiB
    unsigned short* qk    = (unsigned short*)d_out;                  // 32 MiB scratch in d_out

    prep_kernel<<<2048, 256, 0, stream>>>(
        cv1_w, cv1_g, cv1_b, cv1_m, cv1_v, q_w, q_b, k_w, k_b, v_w,
        cv2_w, cv2_g, cv2_b, cv2_m, cv2_v,
        wb1, wqk, wv, wc2, sc1, sh1, sc2, sh2, qkb);

    transpose_x<<<4096, 256, 0, stream>>>(x, xT);

    // cv1: x1 = silu(bn(W1 . x)) -> catT cols [0,256)
    gemm_nt<0><<<dim3(256, 2), 256, 0, stream>>>(xT, 512, wb1, 512, 512,
                                                 catT, 1792, sc1, sh1);

    pool_h<<<512, 256, 0, stream>>>(catT, poolb);
    pool_v<<<dim3(1024, 6), 256, 0, stream>>>(poolb, catT);

    // q,k (stacked, padded to 512 cols) -> qk (in d_out)
    gemm_nt<1><<<dim3(256, 4), 256, 0, stream>>>(catT, 1792, wqk, 1792, 1792,
                                                 qk, 512, qkb, nullptr);

    scores_h<<<512, 256, 0, stream>>>(qk, attHlog);
    scores_w_softmax<<<512, 256, 0, stream>>>(qk, attHlog, attb);

    // per batch-pair: v GEMM + criss-cross apply (result in-place into catT)
    for (int bp = 0; bp < 4; ++bp) {
        const unsigned short* Ap = catT + (long)bp * 8192 * 1792;
        unsigned short* catp     = catT + (long)bp * 8192 * 1792;
        gemm_nt<1><<<dim3(64, 14), 256, 0, stream>>>(Ap, 1792, wv, 1792, 1792,
                                                     vbuf2, 1792, v_b, nullptr);
        apply_att<0><<<512, 256, 0, stream>>>(attb, vbuf2, part2, catp, gamma, bp);
        apply_att<1><<<512, 256, 0, stream>>>(attb, vbuf2, part2, catp, gamma, bp);
    }

    // cv2: silu(bn(W2 . att)) -> fp32 tmp, then transpose to NCHW
    gemm_nt<2><<<dim3(256, 4), 256, 0, stream>>>(catT, 1792, wc2, 1792, 1792,
                                                 cv2tmp, 512, sc2, sh2);
    transpose_out<<<4096, 256, 0, stream>>>(cv2tmp, (float*)d_out);
}

// Round 4
// 775.608 us; speedup vs baseline: 1.5958x; 1.2093x over previous
//
#include <hip/hip_runtime.h>

// ---------------------------------------------------------------------------
// SPPF + criss-cross attention, MI355X bf16-MFMA pipeline.
// Layout convention: "position-major" activations  (B*H*W, C) row-major.
// GEMMs: 256x256 tile, BK=64, 8 waves, 8-phase schedule w/ counted vmcnt.
// ---------------------------------------------------------------------------

typedef short bf16x8 __attribute__((ext_vector_type(8)));
typedef float f32x4  __attribute__((ext_vector_type(4)));

#define DEV __device__ __forceinline__

DEV float bf2f(unsigned short u) {
    unsigned int i = ((unsigned int)u) << 16;
    float f; __builtin_memcpy(&f, &i, 4); return f;
}
DEV unsigned short f2bf(float f) {
    unsigned int i; __builtin_memcpy(&i, &f, 4);
    unsigned int r = i + 0x7FFFu + ((i >> 16) & 1u);
    return (unsigned short)(r >> 16);
}
DEV float fsilu(float v) { return v / (1.f + __expf(-v)); }

// global -> LDS async copy, 16B per lane. LDS base must be wave-uniform.
#define GLL(gsrc, ldst)                                                        \
    __builtin_amdgcn_global_load_lds(                                          \
        (const __attribute__((address_space(1))) unsigned int*)(gsrc),         \
        (__attribute__((address_space(3))) unsigned int*)(ldst), 16, 0, 0)

#define MFMA(a, b, c) __builtin_amdgcn_mfma_f32_16x16x32_bf16((a), (b), (c), 0, 0, 0)

#define SBAR do {                                                              \
    __builtin_amdgcn_sched_barrier(0);                                         \
    __builtin_amdgcn_s_barrier();                                              \
    __builtin_amdgcn_sched_barrier(0); } while (0)
#define LGKM0 do {                                                             \
    asm volatile("s_waitcnt lgkmcnt(0)" ::: "memory");                         \
    __builtin_amdgcn_sched_barrier(0); } while (0)
#define VMC(n) do {                                                            \
    asm volatile("s_waitcnt vmcnt(" #n ")" ::: "memory");                      \
    __builtin_amdgcn_sched_barrier(0); } while (0)

// ---------------------------------------------------------------------------
// prep: fp32 weights -> bf16, stacked/padded qk weights, BN scale/shift vecs
// ---------------------------------------------------------------------------
__global__ __launch_bounds__(256) void prep_kernel(
    const float* __restrict__ cv1_w, const float* __restrict__ cv1_g,
    const float* __restrict__ cv1_b, const float* __restrict__ cv1_m,
    const float* __restrict__ cv1_v,
    const float* __restrict__ q_w, const float* __restrict__ q_b,
    const float* __restrict__ k_w, const float* __restrict__ k_b,
    const float* __restrict__ v_w,
    const float* __restrict__ cv2_w, const float* __restrict__ cv2_g,
    const float* __restrict__ cv2_b, const float* __restrict__ cv2_m,
    const float* __restrict__ cv2_v,
    unsigned short* __restrict__ wb1, unsigned short* __restrict__ wqk,
    unsigned short* __restrict__ wv, unsigned short* __restrict__ wc2,
    float* __restrict__ sc1, float* __restrict__ sh1,
    float* __restrict__ sc2, float* __restrict__ sh2,
    float* __restrict__ qkb)
{
    for (int i = blockIdx.x * 256 + threadIdx.x; i < 3211264;
         i += gridDim.x * 256) {
        wv[i] = f2bf(v_w[i]);
        if (i < 917504) {
            wc2[i] = f2bf(cv2_w[i]);
            int row = i / 1792;
            int col = i - row * 1792;
            float qv = (row < 224) ? q_w[i]
                       : (row < 448) ? k_w[(row - 224) * 1792 + col] : 0.f;
            wqk[i] = f2bf(qv);
        }
        if (i < 131072) wb1[i] = f2bf(cv1_w[i]);
        if (i < 512) {
            qkb[i] = (i < 224) ? q_b[i] : (i < 448 ? k_b[i - 224] : 0.f);
            float sc = cv2_g[i] * rsqrtf(cv2_v[i] + 1e-5f);
            sc2[i] = sc; sh2[i] = cv2_b[i] - cv2_m[i] * sc;
        }
        if (i < 256) {
            float sc = cv1_g[i] * rsqrtf(cv1_v[i] + 1e-5f);
            sc1[i] = sc; sh1[i] = cv1_b[i] - cv1_m[i] * sc;
        }
    }
}

// ---------------------------------------------------------------------------
// transpose x (8,512,4096) fp32  ->  xT (32768, 512) bf16
// ---------------------------------------------------------------------------
__global__ __launch_bounds__(256) void transpose_x(
    const float* __restrict__ x, unsigned short* __restrict__ xT)
{
    int bid = blockIdx.x;               // 8 * 8 * 64 = 4096 blocks
    int nt = bid & 63, ct = (bid >> 6) & 7, b = bid >> 9;
    __shared__ float tile[64][65];
    int tid = threadIdx.x;
    int n0 = nt * 64, c0 = ct * 64;
#pragma unroll
    for (int it = 0; it < 16; ++it) {
        int idx = tid + it * 256;
        int r = idx >> 6, cc = idx & 63;
        tile[r][cc] = x[((long)(b * 512 + c0 + r)) * 4096 + n0 + cc];
    }
    __syncthreads();
#pragma unroll
    for (int it = 0; it < 16; ++it) {
        int idx = tid + it * 256;
        int r = idx >> 6, cc = idx & 63;
        xT[((long)(b * 4096 + n0 + r)) * 512 + c0 + cc] = f2bf(tile[cc][r]);
    }
}

// ---------------------------------------------------------------------------
// transpose cv2tmp (32768,512) fp32 -> d_out (8,512,4096) fp32
// ---------------------------------------------------------------------------
__global__ __launch_bounds__(256) void transpose_out(
    const float* __restrict__ t, float* __restrict__ outp)
{
    int bid = blockIdx.x;               // 8 * 8 * 64 = 4096 blocks
    int nt = bid & 63, ot = (bid >> 6) & 7, b = bid >> 9;
    __shared__ float tile[64][65];
    int tid = threadIdx.x;
    int n0 = nt * 64, o0 = ot * 64;
#pragma unroll
    for (int it = 0; it < 16; ++it) {
        int idx = tid + it * 256;
        int r = idx >> 6, cc = idx & 63;
        tile[r][cc] = t[((long)(b * 4096 + n0 + r)) * 512 + o0 + cc];
    }
    __syncthreads();
#pragma unroll
    for (int it = 0; it < 16; ++it) {
        int idx = tid + it * 256;
        int r = idx >> 6, cc = idx & 63;
        outp[((long)(b * 512 + o0 + r)) * 4096 + n0 + cc] = tile[cc][r];
    }
}

// ---------------------------------------------------------------------------
// 256x256 8-phase NT GEMM. BK=64 (2 k-halves of 32), 8 waves (2M x 4N),
// 512 threads. C[m,n] = sum_k A[m,k]*B[n,k]. LDS 128 KiB, double-buffered.
// K-split halves => phases P1/P2 read only k-half0, P3/P4 only k-half1,
// which makes the counted-vmcnt ledger sound for all waves:
//   stage order (tile kt+1): P1:A-kh0, P2:B-kh0, P3:A-kh1, P4:B-kh1
//   vmcnt(4) end-P2 (this tile's kh1 landed), vmcnt(4) end-P4 (next kh0).
// Swizzle: involution S(byte)=byte^(((byte>>9)&1)<<5) on half-local offsets,
// applied to the GLOBAL source (staging) and the ds_read k-offset (read).
// EPI: 0 = BN+SiLU -> bf16, 1 = +bias -> bf16, 2 = BN+SiLU -> fp32
// ---------------------------------------------------------------------------
template <int EPI>
__global__ __launch_bounds__(512, 2) void gemm256(
    const unsigned short* __restrict__ A, int lda,
    const unsigned short* __restrict__ B, int ldb,
    int K, void* __restrict__ outp, int ldo,
    const float* __restrict__ p0, const float* __restrict__ p1)
{
    __shared__ __align__(16) unsigned short Ash[2][2][8192]; // [dbuf][khalf][256r*32k]
    __shared__ __align__(16) unsigned short Bsh[2][2][8192];
    const int tid = threadIdx.x, lane = tid & 63, wave = tid >> 6;
    const int wm = wave >> 2, wn = wave & 3;           // 2M x 4N wave grid
    const long tile_m = (long)blockIdx.x * 256;
    const long tile_n = (long)blockIdx.y * 256;
    // staging source coords: linear half-offset o = tid*16 (+ j*8192)
    const int r0 = tid >> 2;                            // rows 0..127 (j=0)
    const int ke0 = ((tid & 3) * 8) ^ (16 * ((r0 >> 3) & 1));  // swizzled k-el
    const unsigned short* As0 = A + (tile_m + r0) * (long)lda + ke0;
    const unsigned short* As1 = A + (tile_m + r0 + 128) * (long)lda + ke0;
    const unsigned short* Bs0 = B + (tile_n + r0) * (long)ldb + ke0;
    const unsigned short* Bs1 = B + (tile_n + r0 + 128) * (long)ldb + ke0;
    const int dst0 = wave * 512;          // element offset; HW adds lane*16B
    const int dst1 = 4096 + wave * 512;
    // fragment read coords
    const int arow = lane & 15;
    const int kgs = (((lane >> 4) << 3)) ^ (16 * ((arow >> 3) & 1)); // swizzled
    f32x4 acc[8][4] = {};
    bf16x8 a[8], b[4];
    const int nt = K >> 6;

#define STGA(db, kh, kt) do {                                                  \
    GLL(As0 + (kt) * 64 + (kh) * 32, &Ash[db][kh][dst0]);                      \
    GLL(As1 + (kt) * 64 + (kh) * 32, &Ash[db][kh][dst1]); } while (0)
#define STGB(db, kh, kt) do {                                                  \
    GLL(Bs0 + (kt) * 64 + (kh) * 32, &Bsh[db][kh][dst0]);                      \
    GLL(Bs1 + (kt) * 64 + (kh) * 32, &Bsh[db][kh][dst1]); } while (0)
#define LDA8(db, ks) do { _Pragma("unroll")                                    \
    for (int m = 0; m < 8; ++m)                                                \
        a[m] = *(const bf16x8*)&Ash[db][ks][(wm * 128 + m * 16 + arow) * 32 + kgs]; \
    } while (0)
#define LDB1(db, ks, n, slot)                                                  \
    b[slot] = *(const bf16x8*)&Bsh[db][ks][(wn * 64 + (n) * 16 + arow) * 32 + kgs]
#define MMA2(lo) do {                                                          \
    __builtin_amdgcn_s_setprio(1);                                             \
    _Pragma("unroll")                                                          \
    for (int m = 0; m < 8; ++m) {                                              \
        acc[m][lo]     = MFMA(a[m], b[lo],     acc[m][lo]);                    \
        acc[m][lo + 1] = MFMA(a[m], b[lo + 1], acc[m][lo + 1]);                \
    }                                                                          \
    __builtin_amdgcn_s_setprio(0); } while (0)

    // prologue: stage tile0 fully; need kh0 halves before P1 reads
    STGA(0, 0, 0); STGB(0, 0, 0); STGA(0, 1, 0); STGB(0, 1, 0);
    VMC(4);
    SBAR;

    for (int kt = 0; kt < nt; ++kt) {
        const int db = kt & 1, sb = db ^ 1;
        const bool stg = (kt + 1 < nt);
        const int kn = kt + 1;
        // ---- P1: read a(kh0) + b0,b1(kh0); stage A-kh0(kt+1) ----
        LDA8(db, 0);
        LDB1(db, 0, 0, 0); LDB1(db, 0, 1, 1);
        if (stg) STGA(sb, 0, kn);
        SBAR; LGKM0;
        MMA2(0);
        SBAR;
        // ---- P2: read b2,b3(kh0); stage B-kh0(kt+1) ----
        LDB1(db, 0, 2, 2); LDB1(db, 0, 3, 3);
        if (stg) STGB(sb, 0, kn);
        SBAR; LGKM0;
        MMA2(2);
        if (kt + 1 < nt) { VMC(4); } else { VMC(0); }   // this tile's kh1 landed
        SBAR;
        // ---- P3: read a(kh1) + b0,b1(kh1); stage A-kh1(kt+1) ----
        LDA8(db, 1);
        LDB1(db, 1, 0, 0); LDB1(db, 1, 1, 1);
        if (stg) STGA(sb, 1, kn);
        SBAR; LGKM0;
        MMA2(0);
        SBAR;
        // ---- P4: read b2,b3(kh1); stage B-kh1(kt+1) ----
        LDB1(db, 1, 2, 2); LDB1(db, 1, 3, 3);
        if (stg) STGB(sb, 1, kn);
        SBAR; LGKM0;
        MMA2(2);
        if (stg) VMC(4);                                // next tile's kh0 landed
        SBAR;
    }

    // epilogue
    const int rbase = (lane >> 4) << 2;
#pragma unroll
    for (int n = 0; n < 4; ++n) {
        const int gcol = (int)tile_n + wn * 64 + n * 16 + arow;
        const float s0 = p0[gcol];
        const float s1 = (EPI != 1) ? p1[gcol] : 0.f;
#pragma unroll
        for (int m = 0; m < 8; ++m) {
#pragma unroll
            for (int r = 0; r < 4; ++r) {
                const long grow = tile_m + wm * 128 + m * 16 + rbase + r;
                float v = acc[m][n][r];
                if (EPI != 1) { v = v * s0 + s1; v = fsilu(v); }
                else          { v += s0; }
                if (EPI == 2) ((float*)outp)[grow * ldo + gcol] = v;
                else ((unsigned short*)outp)[grow * ldo + gcol] = f2bf(v);
            }
        }
    }
#undef STGA
#undef STGB
#undef LDA8
#undef LDB1
#undef MMA2
}

// ---------------------------------------------------------------------------
// P1: horizontal (along w) pooling pass. block = (b,h). Produces row-pass
// rmax5/rmax9/rmax13, rsum5/rsum9/rsum13 into 6 pool planes, stored W-MAJOR:
// plane[(b*4096 + w*64 + h)*256 + c]  (so P2 reads contiguous slabs).
// ---------------------------------------------------------------------------
__global__ __launch_bounds__(256) void pool_h(
    const unsigned short* __restrict__ catT, unsigned short* __restrict__ pool)
{
    const int b = blockIdx.x >> 6, h = blockIdx.x & 63;
    __shared__ __align__(16) unsigned short x1s[64 * 256];
    __shared__ __align__(16) unsigned short rm5[64 * 256];
    const int tid = threadIdx.x, lane = tid & 63, wave = tid >> 6;
    const long nb = (long)b * 4096 + h * 64;
#pragma unroll
    for (int j = 0; j < 8; ++j) {
        int o = wave * 8192 + j * 1024 + lane * 16;
        int w = o >> 9, c = (o & 511) >> 1;
        GLL(catT + (nb + w) * 1792 + c,
            (char*)x1s + (wave * 8192 + j * 1024));
    }
    __syncthreads();
    const int c = tid;
    for (int w = 0; w < 64; ++w) {
        int lo = (w >= 2) ? w - 2 : 0, hi = (w <= 61) ? w + 2 : 63;
        float m = bf2f(x1s[lo * 256 + c]);
        for (int d = lo + 1; d <= hi; ++d) m = fmaxf(m, bf2f(x1s[d * 256 + c]));
        rm5[w * 256 + c] = f2bf(m);
    }
    float s5 = 0.f, s9 = 0.f, s13 = 0.f;
#pragma unroll
    for (int d = 0; d <= 2; ++d) s5  += bf2f(x1s[d * 256 + c]);
#pragma unroll
    for (int d = 0; d <= 4; ++d) s9  += bf2f(x1s[d * 256 + c]);
#pragma unroll
    for (int d = 0; d <= 6; ++d) s13 += bf2f(x1s[d * 256 + c]);
    unsigned short* q0 = pool;
    unsigned short* q1 = pool + (long)32768 * 256;
    unsigned short* q2 = pool + (long)32768 * 512;
    unsigned short* q3 = pool + (long)32768 * 768;
    unsigned short* q4 = pool + (long)32768 * 1024;
    unsigned short* q5 = pool + (long)32768 * 1280;
    const long wb = (long)b * 4096 + h;          // w-major dest base
    for (int w = 0; w < 64; ++w) {
        long off = (wb + (long)w * 64) * 256 + c;
        float v5 = bf2f(rm5[w * 256 + c]);
        int wm2 = (w >= 2) ? w - 2 : 0, wp2 = (w <= 61) ? w + 2 : 63;
        int wm4 = (w >= 4) ? w - 4 : 0, wp4 = (w <= 59) ? w + 4 : 63;
        float v9  = fmaxf(bf2f(rm5[wm2 * 256 + c]), bf2f(rm5[wp2 * 256 + c]));
        float v13 = fmaxf(v5, fmaxf(bf2f(rm5[wm4 * 256 + c]),
                                    bf2f(rm5[wp4 * 256 + c])));
        q0[off] = f2bf(v5);  q1[off] = f2bf(v9);  q2[off] = f2bf(v13);
        q3[off] = f2bf(s5);  q4[off] = f2bf(s9);  q5[off] = f2bf(s13);
        if (w + 3 <= 63) s5  += bf2f(x1s[(w + 3) * 256 + c]);
        if (w - 2 >= 0)  s5  -= bf2f(x1s[(w - 2) * 256 + c]);
        if (w + 5 <= 63) s9  += bf2f(x1s[(w + 5) * 256 + c]);
        if (w - 4 >= 0)  s9  -= bf2f(x1s[(w - 4) * 256 + c]);
        if (w + 7 <= 63) s13 += bf2f(x1s[(w + 7) * 256 + c]);
        if (w - 6 >= 0)  s13 -= bf2f(x1s[(w - 6) * 256 + c]);
    }
}

// ---------------------------------------------------------------------------
// P2: vertical (along h) pass. grid (1024, 6): x = (b, w, c-half), y = section.
// ---------------------------------------------------------------------------
__global__ __launch_bounds__(256) void pool_v(
    const unsigned short* __restrict__ pool, unsigned short* __restrict__ catT)
{
    const int s6 = blockIdx.y;
    const int bid = blockIdx.x;
    const int chh = bid & 1, w = (bid >> 1) & 63, b = bid >> 7;
    const int c0 = chh * 128;
    __shared__ __align__(16) unsigned short slab[64 * 128];
    const int tid = threadIdx.x, lane = tid & 63, wave = tid >> 6;
    const unsigned short* src = pool + (long)s6 * 32768 * 256 +
                                ((long)b * 4096 + (long)w * 64) * 256 + c0;
#pragma unroll
    for (int j = 0; j < 4; ++j) {
        int o = j * 4096 + wave * 1024 + lane * 16;
        int hh = o >> 8, ce = (o & 255) >> 1;
        GLL(src + hh * 256 + ce, (char*)slab + (j * 4096 + wave * 1024));
    }
    __syncthreads();
    const int c = tid & 127, hg = tid >> 7;
    const int rr[6]   = {2, 4, 6, 2, 4, 6};
    const int dsec[6] = {256, 512, 768, 1536, 1280, 1024};
    const float scl[6] = {0.f, 0.f, 0.f, 1.f / 25.f, 1.f / 81.f, 1.f / 169.f};
    const int r = rr[s6];
    const long dbase = ((long)b * 4096 + w) * 1792 + dsec[s6] + c0 + c;
    const int h0 = hg * 32;
    if (s6 < 3) {
        for (int hh = 0; hh < 32; ++hh) {
            int h = h0 + hh;
            int lo = (h - r >= 0) ? h - r : 0, hi = (h + r <= 63) ? h + r : 63;
            float m = bf2f(slab[lo * 128 + c]);
            for (int d = lo + 1; d <= hi; ++d)
                m = fmaxf(m, bf2f(slab[d * 128 + c]));
            catT[dbase + (long)h * (64 * 1792)] = f2bf(m);
        }
    } else {
        float s = 0.f;
        int lo0 = (h0 - r >= 0) ? h0 - r : 0, hi0 = (h0 + r <= 63) ? h0 + r : 63;
        for (int d = lo0; d <= hi0; ++d) s += bf2f(slab[d * 128 + c]);
        const float sc = scl[s6];
        for (int hh = 0; hh < 32; ++hh) {
            int h = h0 + hh;
            catT[dbase + (long)h * (64 * 1792)] = f2bf(s * sc);
            if (h + 1 + r <= 63) s += bf2f(slab[(h + 1 + r) * 128 + c]);
            if (h - r >= 0)      s -= bf2f(slab[(h - r) * 128 + c]);
        }
    }
}

// ---------------------------------------------------------------------------
// S1: eH scores, block = (b, w).
// ---------------------------------------------------------------------------
__global__ __launch_bounds__(256) void scores_h(
    const unsigned short* __restrict__ qk, float* __restrict__ attHlog)
{
    const int b = blockIdx.x >> 6, w = blockIdx.x & 63;
    __shared__ __align__(16) unsigned short Qs[64 * 232];
    __shared__ __align__(16) unsigned short Ks[64 * 232];
    const int tid = threadIdx.x, lane = tid & 63, wave = tid >> 6;
#pragma unroll
    for (int j = 0; j < 14; ++j) {
        int idx = tid + j * 256;
        int s = idx >= 1792;
        int id2 = idx - s * 1792;
        int row = id2 / 28, cb = id2 - row * 28;
        bf16x8 v = *(const bf16x8*)(qk + ((long)b * 4096 + row * 64 + w) * 512 +
                                    s * 224 + cb * 8);
        *(bf16x8*)((s ? Ks : Qs) + row * 232 + cb * 8) = v;
    }
    __syncthreads();
    const int m0 = wave * 16, arow = lane & 15, kc = (lane >> 4) << 3;
    f32x4 acc[4] = {};
#pragma unroll
    for (int ks = 0; ks < 7; ++ks) {
        bf16x8 af = *(const bf16x8*)(Qs + (m0 + arow) * 232 + ks * 32 + kc);
#pragma unroll
        for (int nf = 0; nf < 4; ++nf) {
            bf16x8 bv = *(const bf16x8*)(Ks + (nf * 16 + arow) * 232 + ks * 32 + kc);
            acc[nf] = MFMA(af, bv, acc[nf]);
        }
    }
    const int rb = (lane >> 4) << 2;
#pragma unroll
    for (int nf = 0; nf < 4; ++nf) {
        int g = nf * 16 + arow;
#pragma unroll
        for (int r = 0; r < 4; ++r) {
            int h = m0 + rb + r;
            float v = acc[nf][r];
            if (g == h) v = -1e30f;
            attHlog[((long)(b * 64 + h) * 64 + w) * 64 + g] = v;
        }
    }
}

// ---------------------------------------------------------------------------
// S2: eW scores + fused softmax over concat([eH, eW], 128). block = (b, h).
// ---------------------------------------------------------------------------
__global__ __launch_bounds__(256) void scores_w_softmax(
    const unsigned short* __restrict__ qk, const float* __restrict__ attHlog,
    unsigned short* __restrict__ att)
{
    const int b = blockIdx.x >> 6, h = blockIdx.x & 63;
    __shared__ __align__(16) unsigned short Qs[64 * 232];
    __shared__ __align__(16) unsigned short Ks[64 * 232];
    __shared__ float ews[64 * 65];
    const int tid = threadIdx.x, lane = tid & 63, wave = tid >> 6;
    const long nbase = (long)b * 4096 + h * 64;
#pragma unroll
    for (int j = 0; j < 14; ++j) {
        int idx = tid + j * 256;
        int s = idx >= 1792;
        int id2 = idx - s * 1792;
        int row = id2 / 28, cb = id2 - row * 28;
        bf16x8 v = *(const bf16x8*)(qk + (nbase + row) * 512 + s * 224 + cb * 8);
        *(bf16x8*)((s ? Ks : Qs) + row * 232 + cb * 8) = v;
    }
    __syncthreads();
    const int m0 = wave * 16, arow = lane & 15, kc = (lane >> 4) << 3;
    f32x4 acc[4] = {};
#pragma unroll
    for (int ks = 0; ks < 7; ++ks) {
        bf16x8 af = *(const bf16x8*)(Qs + (m0 + arow) * 232 + ks * 32 + kc);
#pragma unroll
        for (int nf = 0; nf < 4; ++nf) {
            bf16x8 bv = *(const bf16x8*)(Ks + (nf * 16 + arow) * 232 + ks * 32 + kc);
            acc[nf] = MFMA(af, bv, acc[nf]);
        }
    }
    const int rb = (lane >> 4) << 2;
#pragma unroll
    for (int nf = 0; nf < 4; ++nf)
#pragma unroll
        for (int r = 0; r < 4; ++r)
            ews[(m0 + rb + r) * 65 + nf * 16 + arow] = acc[nf][r];
    __syncthreads();
    const int wl = tid >> 2, p = tid & 3;
    float eh[16], ew[16];
    const float* hrow = attHlog + ((long)(b * 64 + h) * 64 + wl) * 64 + p * 16;
#pragma unroll
    for (int j = 0; j < 16; ++j) eh[j] = hrow[j];
#pragma unroll
    for (int j = 0; j < 16; ++j) ew[j] = ews[wl * 65 + p * 16 + j];
    float mx = -1e30f;
#pragma unroll
    for (int j = 0; j < 16; ++j) { mx = fmaxf(mx, eh[j]); mx = fmaxf(mx, ew[j]); }
    mx = fmaxf(mx, __shfl_xor(mx, 1));
    mx = fmaxf(mx, __shfl_xor(mx, 2));
    float sm = 0.f;
#pragma unroll
    for (int j = 0; j < 16; ++j) {
        eh[j] = __expf(eh[j] - mx); sm += eh[j];
        ew[j] = __expf(ew[j] - mx); sm += ew[j];
    }
    sm += __shfl_xor(sm, 1);
    sm += __shfl_xor(sm, 2);
    float inv = 1.f / sm;
    unsigned short* orow = att + ((long)(b * 64 + h) * 64 + wl) * 128;
#pragma unroll
    for (int j = 0; j < 16; ++j) orow[p * 16 + j] = f2bf(eh[j] * inv);
#pragma unroll
    for (int j = 0; j < 16; ++j) orow[64 + p * 16 + j] = f2bf(ew[j] * inv);
}

// ---------------------------------------------------------------------------
// apply_att (per batch-pair bp): grid 512 = lb(2) x i(64) x chunk(4).
// ---------------------------------------------------------------------------
template <int MODE>
__global__ __launch_bounds__(256) void apply_att(
    const unsigned short* __restrict__ att, const unsigned short* __restrict__ vb,
    unsigned short* __restrict__ part, unsigned short* __restrict__ cat,
    const float* __restrict__ gamma, int bp)
{
    const int ch = blockIdx.x & 3;
    const int i  = (blockIdx.x >> 2) & 63;
    const int lb = blockIdx.x >> 8;
    const int b  = bp * 2 + lb;
    const int c0 = ch * 448;
    __shared__ __align__(16) unsigned short As[64 * 72];
    __shared__ __align__(16) unsigned short Vs[64 * 448];
    const int tid = threadIdx.x, lane = tid & 63, wave = tid >> 6;
#pragma unroll
    for (int j = 0; j < 2; ++j) {
        int idx = tid + j * 256;
        int hh = idx >> 3, cb = idx & 7;
        long pos = (MODE == 0) ? ((long)(b * 64 + hh) * 64 + i)
                               : ((long)(b * 64 + i) * 64 + hh);
        bf16x8 v = *(const bf16x8*)(att + pos * 128 + MODE * 64 + cb * 8);
        *(bf16x8*)(As + hh * 72 + cb * 8) = v;
    }
#pragma unroll
    for (int j = 0; j < 14; ++j) {
        int idx = tid + j * 256;
        int g = idx / 56, cb = idx - g * 56;
        long n = (MODE == 0) ? ((long)lb * 4096 + g * 64 + i)
                             : ((long)lb * 4096 + i * 64 + g);
        bf16x8 v = *(const bf16x8*)(vb + n * 1792 + c0 + cb * 8);
        int sw = (g >> 3) & 7;
        *(bf16x8*)(Vs + g * 448 + ((cb ^ sw) << 3)) = v;
    }
    __syncthreads();
    const int arow = lane & 15, kc8 = (lane >> 4) << 3;
    const int rb = (lane >> 4) << 2;
    f32x4 acc[4][7] = {};
#pragma unroll
    for (int ks = 0; ks < 2; ++ks) {
        const int k0 = ks * 32;
        bf16x8 af[4];
#pragma unroll
        for (int m = 0; m < 4; ++m)
            af[m] = *(const bf16x8*)(As + (m * 16 + arow) * 72 + k0 + kc8);
        const int g0 = k0 + kc8;
        const int sw = (g0 >> 3) & 7;
#pragma unroll
        for (int nf = 0; nf < 7; ++nf) {
            int cl = wave * 112 + nf * 16 + arow;
            int cb = cl >> 3, clo = cl & 7;
            const unsigned short* pp = Vs + g0 * 448 + ((cb ^ sw) << 3) + clo;
            bf16x8 bv;
#pragma unroll
            for (int j = 0; j < 8; ++j) bv[j] = (short)pp[j * 448];
#pragma unroll
            for (int m = 0; m < 4; ++m)
                acc[m][nf] = MFMA(af[m], bv, acc[m][nf]);
        }
    }
    const float gam = gamma[0];
#pragma unroll
    for (int nf = 0; nf < 7; ++nf) {
        const int c = c0 + wave * 112 + nf * 16 + arow;
#pragma unroll
        for (int m = 0; m < 4; ++m) {
#pragma unroll
            for (int r = 0; r < 4; ++r) {
                const int rl = m * 16 + rb + r;
                long n = (MODE == 0) ? ((long)lb * 4096 + rl * 64 + i)
                                     : ((long)lb * 4096 + i * 64 + rl);
                long idx2 = n * 1792 + c;
                if (MODE == 0) {
                    part[idx2] = f2bf(acc[m][nf][r]);
                } else {
                    float pv = bf2f(part[idx2]);
                    float cv = bf2f(cat[idx2]);
                    cat[idx2] = f2bf(gam * (acc[m][nf][r] + pv) + cv);
                }
            }
        }
    }
}

// ---------------------------------------------------------------------------
// launcher
// ---------------------------------------------------------------------------
extern "C" void kernel_launch(void* const* d_in, const int* in_sizes, int n_in,
                              void* d_out, int out_size, void* d_ws, size_t ws_size,
                              hipStream_t stream)
{
    const float* x     = (const float*)d_in[0];
    const float* cv1_w = (const float*)d_in[1];
    const float* cv1_g = (const float*)d_in[2];
    const float* cv1_b = (const float*)d_in[3];
    const float* cv1_m = (const float*)d_in[4];
    const float* cv1_v = (const float*)d_in[5];
    const float* q_w   = (const float*)d_in[6];
    const float* q_b   = (const float*)d_in[7];
    const float* k_w   = (const float*)d_in[8];
    const float* k_b   = (const float*)d_in[9];
    const float* v_w   = (const float*)d_in[10];
    const float* v_b   = (const float*)d_in[11];
    const float* gamma = (const float*)d_in[12];
    const float* cv2_w = (const float*)d_in[13];
    const float* cv2_g = (const float*)d_in[14];
    const float* cv2_b = (const float*)d_in[15];
    const float* cv2_m = (const float*)d_in[16];
    const float* cv2_v = (const float*)d_in[17];

    char* ws = (char*)d_ws;
    // ---- workspace map (total 229,638,144 B = 219 MiB) ----
    unsigned short* wb1  = (unsigned short*)(ws + 0);          //  256x512
    unsigned short* wqk  = (unsigned short*)(ws + 262144);     //  512x1792
    unsigned short* wv   = (unsigned short*)(ws + 2097152);    // 1792x1792
    unsigned short* wc2  = (unsigned short*)(ws + 8519680);    //  512x1792
    float* sc1           = (float*)(ws + 10354688);
    float* sh1           = (float*)(ws + 10358784);
    float* sc2           = (float*)(ws + 10362880);
    float* sh2           = (float*)(ws + 10366976);
    float* qkb           = (float*)(ws + 10371072);
    unsigned short* catT = (unsigned short*)(ws + 11534336);   // 32768x1792, live to end
    const long C_OFF = 128974848;                              // 96 MiB time-shared region
    unsigned short* xT    = (unsigned short*)(ws + C_OFF);           // ph1: 32 MiB
    unsigned short* poolb = (unsigned short*)(ws + C_OFF);           // ph2: 96 MiB
    float* attHlog        = (float*)(ws + C_OFF);                    // ph3: 8 MiB
    unsigned short* attb  = (unsigned short*)(ws + C_OFF + 8388608); // ph3: 8 MiB
    unsigned short* vbuf2 = (unsigned short*)(ws + C_OFF + 16777216);// ph3: 28 MiB/pair
    unsigned short* part2 = (unsigned short*)(ws + C_OFF + 46137344);// ph3: 28 MiB/pair
    float* cv2tmp         = (float*)(ws + C_OFF + 16777216);         // ph4: 64 MiB
    unsigned short* qk    = (unsigned short*)d_out;                  // 32 MiB scratch in d_out

    prep_kernel<<<2048, 256, 0, stream>>>(
        cv1_w, cv1_g, cv1_b, cv1_m, cv1_v, q_w, q_b, k_w, k_b, v_w,
        cv2_w, cv2_g, cv2_b, cv2_m, cv2_v,
        wb1, wqk, wv, wc2, sc1, sh1, sc2, sh2, qkb);

    transpose_x<<<4096, 256, 0, stream>>>(x, xT);

    // cv1: x1 = silu(bn(W1 . x)) -> catT cols [0,256)
    gemm256<0><<<dim3(128, 1), 512, 0, stream>>>(xT, 512, wb1, 512, 512,
                                                 catT, 1792, sc1, sh1);

    pool_h<<<512, 256, 0, stream>>>(catT, poolb);
    pool_v<<<dim3(1024, 6), 256, 0, stream>>>(poolb, catT);

    // q,k (stacked, padded to 512 cols) -> qk (in d_out)
    gemm256<1><<<dim3(128, 2), 512, 0, stream>>>(catT, 1792, wqk, 1792, 1792,
                                                 qk, 512, qkb, nullptr);

    scores_h<<<512, 256, 0, stream>>>(qk, attHlog);
    scores_w_softmax<<<512, 256, 0, stream>>>(qk, attHlog, attb);

    // per batch-pair: v GEMM + criss-cross apply (result in-place into catT)
    for (int bp = 0; bp < 4; ++bp) {
        const unsigned short* Ap = catT + (long)bp * 8192 * 1792;
        unsigned short* catp     = catT + (long)bp * 8192 * 1792;
        gemm256<1><<<dim3(32, 7), 512, 0, stream>>>(Ap, 1792, wv, 1792, 1792,
                                                    vbuf2, 1792, v_b, nullptr);
        apply_att<0><<<512, 256, 0, stream>>>(attb, vbuf2, part2, catp, gamma, bp);
        apply_att<1><<<512, 256, 0, stream>>>(attb, vbuf2, part2, catp, gamma, bp);
    }

    // cv2: silu(bn(W2 . att)) -> fp32 tmp, then transpose to NCHW
    gemm256<2><<<dim3(128, 2), 512, 0, stream>>>(catT, 1792, wc2, 1792, 1792,
                                                 cv2tmp, 512, sc2, sh2);
    transpose_out<<<4096, 256, 0, stream>>>(cv2tmp, (float*)d_out);
}

// Round 5
// 772.085 us; speedup vs baseline: 1.6031x; 1.0046x over previous
//
#include <hip/hip_runtime.h>

// ---------------------------------------------------------------------------
// SPPF + criss-cross attention, MI355X bf16-MFMA pipeline.
// Layout convention: "position-major" activations  (B*H*W, C) row-major.
// GEMMs: 256x256 tile, BK=64, 8 waves, 8-phase schedule w/ counted vmcnt.
// pool_v: van Herk sliding-window max (templated radius, reg-resident prefix).
// ---------------------------------------------------------------------------

typedef short bf16x8 __attribute__((ext_vector_type(8)));
typedef float f32x4  __attribute__((ext_vector_type(4)));

#define DEV __device__ __forceinline__

DEV float bf2f(unsigned short u) {
    unsigned int i = ((unsigned int)u) << 16;
    float f; __builtin_memcpy(&f, &i, 4); return f;
}
DEV unsigned short f2bf(float f) {
    unsigned int i; __builtin_memcpy(&i, &f, 4);
    unsigned int r = i + 0x7FFFu + ((i >> 16) & 1u);
    return (unsigned short)(r >> 16);
}
DEV float fsilu(float v) { return v / (1.f + __expf(-v)); }

// global -> LDS async copy, 16B per lane. LDS base must be wave-uniform.
#define GLL(gsrc, ldst)                                                        \
    __builtin_amdgcn_global_load_lds(                                          \
        (const __attribute__((address_space(1))) unsigned int*)(gsrc),         \
        (__attribute__((address_space(3))) unsigned int*)(ldst), 16, 0, 0)

#define MFMA(a, b, c) __builtin_amdgcn_mfma_f32_16x16x32_bf16((a), (b), (c), 0, 0, 0)

#define SBAR do {                                                              \
    __builtin_amdgcn_sched_barrier(0);                                         \
    __builtin_amdgcn_s_barrier();                                              \
    __builtin_amdgcn_sched_barrier(0); } while (0)
#define LGKM0 do {                                                             \
    asm volatile("s_waitcnt lgkmcnt(0)" ::: "memory");                         \
    __builtin_amdgcn_sched_barrier(0); } while (0)
#define VMC(n) do {                                                            \
    asm volatile("s_waitcnt vmcnt(" #n ")" ::: "memory");                      \
    __builtin_amdgcn_sched_barrier(0); } while (0)

// ---------------------------------------------------------------------------
// prep: fp32 weights -> bf16, stacked/padded qk weights, BN scale/shift vecs
// ---------------------------------------------------------------------------
__global__ __launch_bounds__(256) void prep_kernel(
    const float* __restrict__ cv1_w, const float* __restrict__ cv1_g,
    const float* __restrict__ cv1_b, const float* __restrict__ cv1_m,
    const float* __restrict__ cv1_v,
    const float* __restrict__ q_w, const float* __restrict__ q_b,
    const float* __restrict__ k_w, const float* __restrict__ k_b,
    const float* __restrict__ v_w,
    const float* __restrict__ cv2_w, const float* __restrict__ cv2_g,
    const float* __restrict__ cv2_b, const float* __restrict__ cv2_m,
    const float* __restrict__ cv2_v,
    unsigned short* __restrict__ wb1, unsigned short* __restrict__ wqk,
    unsigned short* __restrict__ wv, unsigned short* __restrict__ wc2,
    float* __restrict__ sc1, float* __restrict__ sh1,
    float* __restrict__ sc2, float* __restrict__ sh2,
    float* __restrict__ qkb)
{
    for (int i = blockIdx.x * 256 + threadIdx.x; i < 3211264;
         i += gridDim.x * 256) {
        wv[i] = f2bf(v_w[i]);
        if (i < 917504) {
            wc2[i] = f2bf(cv2_w[i]);
            int row = i / 1792;
            int col = i - row * 1792;
            float qv = (row < 224) ? q_w[i]
                       : (row < 448) ? k_w[(row - 224) * 1792 + col] : 0.f;
            wqk[i] = f2bf(qv);
        }
        if (i < 131072) wb1[i] = f2bf(cv1_w[i]);
        if (i < 512) {
            qkb[i] = (i < 224) ? q_b[i] : (i < 448 ? k_b[i - 224] : 0.f);
            float sc = cv2_g[i] * rsqrtf(cv2_v[i] + 1e-5f);
            sc2[i] = sc; sh2[i] = cv2_b[i] - cv2_m[i] * sc;
        }
        if (i < 256) {
            float sc = cv1_g[i] * rsqrtf(cv1_v[i] + 1e-5f);
            sc1[i] = sc; sh1[i] = cv1_b[i] - cv1_m[i] * sc;
        }
    }
}

// ---------------------------------------------------------------------------
// transpose x (8,512,4096) fp32  ->  xT (32768, 512) bf16
// ---------------------------------------------------------------------------
__global__ __launch_bounds__(256) void transpose_x(
    const float* __restrict__ x, unsigned short* __restrict__ xT)
{
    int bid = blockIdx.x;               // 8 * 8 * 64 = 4096 blocks
    int nt = bid & 63, ct = (bid >> 6) & 7, b = bid >> 9;
    __shared__ float tile[64][65];
    int tid = threadIdx.x;
    int n0 = nt * 64, c0 = ct * 64;
#pragma unroll
    for (int it = 0; it < 16; ++it) {
        int idx = tid + it * 256;
        int r = idx >> 6, cc = idx & 63;
        tile[r][cc] = x[((long)(b * 512 + c0 + r)) * 4096 + n0 + cc];
    }
    __syncthreads();
#pragma unroll
    for (int it = 0; it < 16; ++it) {
        int idx = tid + it * 256;
        int r = idx >> 6, cc = idx & 63;
        xT[((long)(b * 4096 + n0 + r)) * 512 + c0 + cc] = f2bf(tile[cc][r]);
    }
}

// ---------------------------------------------------------------------------
// transpose cv2tmp (32768,512) fp32 -> d_out (8,512,4096) fp32
// ---------------------------------------------------------------------------
__global__ __launch_bounds__(256) void transpose_out(
    const float* __restrict__ t, float* __restrict__ outp)
{
    int bid = blockIdx.x;               // 8 * 8 * 64 = 4096 blocks
    int nt = bid & 63, ot = (bid >> 6) & 7, b = bid >> 9;
    __shared__ float tile[64][65];
    int tid = threadIdx.x;
    int n0 = nt * 64, o0 = ot * 64;
#pragma unroll
    for (int it = 0; it < 16; ++it) {
        int idx = tid + it * 256;
        int r = idx >> 6, cc = idx & 63;
        tile[r][cc] = t[((long)(b * 4096 + n0 + r)) * 512 + o0 + cc];
    }
    __syncthreads();
#pragma unroll
    for (int it = 0; it < 16; ++it) {
        int idx = tid + it * 256;
        int r = idx >> 6, cc = idx & 63;
        outp[((long)(b * 512 + o0 + r)) * 4096 + n0 + cc] = tile[cc][r];
    }
}

// ---------------------------------------------------------------------------
// 256x256 8-phase NT GEMM. BK=64 (2 k-halves of 32), 8 waves (2M x 4N),
// 512 threads. C[m,n] = sum_k A[m,k]*B[n,k]. LDS 128 KiB, double-buffered.
// vmcnt ledger: stage order P1:A-kh0, P2:B-kh0, P3:A-kh1, P4:B-kh1 (2 GLL ea);
// vmcnt(4) end-P2 (this tile's kh1 landed), vmcnt(4) end-P4 (next kh0).
// Swizzle: S(byte)=byte^(((byte>>9)&1)<<5) applied to GLOBAL source (staging)
// and the ds_read k-offset (read) -- both-sides involution.
// EPI: 0 = BN+SiLU -> bf16, 1 = +bias -> bf16, 2 = BN+SiLU -> fp32
// ---------------------------------------------------------------------------
template <int EPI>
__global__ __launch_bounds__(512, 2) void gemm256(
    const unsigned short* __restrict__ A, int lda,
    const unsigned short* __restrict__ B, int ldb,
    int K, void* __restrict__ outp, int ldo,
    const float* __restrict__ p0, const float* __restrict__ p1)
{
    __shared__ __align__(16) unsigned short Ash[2][2][8192]; // [dbuf][khalf][256r*32k]
    __shared__ __align__(16) unsigned short Bsh[2][2][8192];
    const int tid = threadIdx.x, lane = tid & 63, wave = tid >> 6;
    const int wm = wave >> 2, wn = wave & 3;           // 2M x 4N wave grid
    const long tile_m = (long)blockIdx.x * 256;
    const long tile_n = (long)blockIdx.y * 256;
    const int r0 = tid >> 2;                            // rows 0..127 (j=0)
    const int ke0 = ((tid & 3) * 8) ^ (16 * ((r0 >> 3) & 1));  // swizzled k-el
    const unsigned short* As0 = A + (tile_m + r0) * (long)lda + ke0;
    const unsigned short* As1 = A + (tile_m + r0 + 128) * (long)lda + ke0;
    const unsigned short* Bs0 = B + (tile_n + r0) * (long)ldb + ke0;
    const unsigned short* Bs1 = B + (tile_n + r0 + 128) * (long)ldb + ke0;
    const int dst0 = wave * 512;          // element offset; HW adds lane*16B
    const int dst1 = 4096 + wave * 512;
    const int arow = lane & 15;
    const int kgs = (((lane >> 4) << 3)) ^ (16 * ((arow >> 3) & 1)); // swizzled
    f32x4 acc[8][4] = {};
    bf16x8 a[8], b[4];
    const int nt = K >> 6;

#define STGA(db, kh, kt) do {                                                  \
    GLL(As0 + (kt) * 64 + (kh) * 32, &Ash[db][kh][dst0]);                      \
    GLL(As1 + (kt) * 64 + (kh) * 32, &Ash[db][kh][dst1]); } while (0)
#define STGB(db, kh, kt) do {                                                  \
    GLL(Bs0 + (kt) * 64 + (kh) * 32, &Bsh[db][kh][dst0]);                      \
    GLL(Bs1 + (kt) * 64 + (kh) * 32, &Bsh[db][kh][dst1]); } while (0)
#define LDA8(db, ks) do { _Pragma("unroll")                                    \
    for (int m = 0; m < 8; ++m)                                                \
        a[m] = *(const bf16x8*)&Ash[db][ks][(wm * 128 + m * 16 + arow) * 32 + kgs]; \
    } while (0)
#define LDB1(db, ks, n, slot)                                                  \
    b[slot] = *(const bf16x8*)&Bsh[db][ks][(wn * 64 + (n) * 16 + arow) * 32 + kgs]
#define MMA2(lo) do {                                                          \
    __builtin_amdgcn_s_setprio(1);                                             \
    _Pragma("unroll")                                                          \
    for (int m = 0; m < 8; ++m) {                                              \
        acc[m][lo]     = MFMA(a[m], b[lo],     acc[m][lo]);                    \
        acc[m][lo + 1] = MFMA(a[m], b[lo + 1], acc[m][lo + 1]);                \
    }                                                                          \
    __builtin_amdgcn_s_setprio(0); } while (0)

    STGA(0, 0, 0); STGB(0, 0, 0); STGA(0, 1, 0); STGB(0, 1, 0);
    VMC(4);
    SBAR;

    for (int kt = 0; kt < nt; ++kt) {
        const int db = kt & 1, sb = db ^ 1;
        const bool stg = (kt + 1 < nt);
        const int kn = kt + 1;
        // ---- P1 ----
        LDA8(db, 0);
        LDB1(db, 0, 0, 0); LDB1(db, 0, 1, 1);
        if (stg) STGA(sb, 0, kn);
        SBAR; LGKM0;
        MMA2(0);
        SBAR;
        // ---- P2 ----
        LDB1(db, 0, 2, 2); LDB1(db, 0, 3, 3);
        if (stg) STGB(sb, 0, kn);
        SBAR; LGKM0;
        MMA2(2);
        if (kt + 1 < nt) { VMC(4); } else { VMC(0); }
        SBAR;
        // ---- P3 ----
        LDA8(db, 1);
        LDB1(db, 1, 0, 0); LDB1(db, 1, 1, 1);
        if (stg) STGA(sb, 1, kn);
        SBAR; LGKM0;
        MMA2(0);
        SBAR;
        // ---- P4 ----
        LDB1(db, 1, 2, 2); LDB1(db, 1, 3, 3);
        if (stg) STGB(sb, 1, kn);
        SBAR; LGKM0;
        MMA2(2);
        if (stg) VMC(4);
        SBAR;
    }

    const int rbase = (lane >> 4) << 2;
#pragma unroll
    for (int n = 0; n < 4; ++n) {
        const int gcol = (int)tile_n + wn * 64 + n * 16 + arow;
        const float s0 = p0[gcol];
        const float s1 = (EPI != 1) ? p1[gcol] : 0.f;
#pragma unroll
        for (int m = 0; m < 8; ++m) {
#pragma unroll
            for (int r = 0; r < 4; ++r) {
                const long grow = tile_m + wm * 128 + m * 16 + rbase + r;
                float v = acc[m][n][r];
                if (EPI != 1) { v = v * s0 + s1; v = fsilu(v); }
                else          { v += s0; }
                if (EPI == 2) ((float*)outp)[grow * ldo + gcol] = v;
                else ((unsigned short*)outp)[grow * ldo + gcol] = f2bf(v);
            }
        }
    }
#undef STGA
#undef STGB
#undef LDA8
#undef LDB1
#undef MMA2
}

// ---------------------------------------------------------------------------
// P1: horizontal (along w) pooling pass. block = (b,h). Produces row-pass
// rmax5/rmax9/rmax13, rsum5/rsum9/rsum13 into 6 pool planes, stored W-MAJOR:
// plane[(b*4096 + w*64 + h)*256 + c]  (so P2 reads contiguous slabs).
// ---------------------------------------------------------------------------
__global__ __launch_bounds__(256) void pool_h(
    const unsigned short* __restrict__ catT, unsigned short* __restrict__ pool)
{
    const int b = blockIdx.x >> 6, h = blockIdx.x & 63;
    __shared__ __align__(16) unsigned short x1s[64 * 256];
    __shared__ __align__(16) unsigned short rm5[64 * 256];
    const int tid = threadIdx.x, lane = tid & 63, wave = tid >> 6;
    const long nb = (long)b * 4096 + h * 64;
#pragma unroll
    for (int j = 0; j < 8; ++j) {
        int o = wave * 8192 + j * 1024 + lane * 16;
        int w = o >> 9, c = (o & 511) >> 1;
        GLL(catT + (nb + w) * 1792 + c,
            (char*)x1s + (wave * 8192 + j * 1024));
    }
    __syncthreads();
    const int c = tid;
    for (int w = 0; w < 64; ++w) {
        int lo = (w >= 2) ? w - 2 : 0, hi = (w <= 61) ? w + 2 : 63;
        float m = bf2f(x1s[lo * 256 + c]);
        for (int d = lo + 1; d <= hi; ++d) m = fmaxf(m, bf2f(x1s[d * 256 + c]));
        rm5[w * 256 + c] = f2bf(m);
    }
    float s5 = 0.f, s9 = 0.f, s13 = 0.f;
#pragma unroll
    for (int d = 0; d <= 2; ++d) s5  += bf2f(x1s[d * 256 + c]);
#pragma unroll
    for (int d = 0; d <= 4; ++d) s9  += bf2f(x1s[d * 256 + c]);
#pragma unroll
    for (int d = 0; d <= 6; ++d) s13 += bf2f(x1s[d * 256 + c]);
    unsigned short* q0 = pool;
    unsigned short* q1 = pool + (long)32768 * 256;
    unsigned short* q2 = pool + (long)32768 * 512;
    unsigned short* q3 = pool + (long)32768 * 768;
    unsigned short* q4 = pool + (long)32768 * 1024;
    unsigned short* q5 = pool + (long)32768 * 1280;
    const long wb = (long)b * 4096 + h;          // w-major dest base
    for (int w = 0; w < 64; ++w) {
        long off = (wb + (long)w * 64) * 256 + c;
        float v5 = bf2f(rm5[w * 256 + c]);
        int wm2 = (w >= 2) ? w - 2 : 0, wp2 = (w <= 61) ? w + 2 : 63;
        int wm4 = (w >= 4) ? w - 4 : 0, wp4 = (w <= 59) ? w + 4 : 63;
        float v9  = fmaxf(bf2f(rm5[wm2 * 256 + c]), bf2f(rm5[wp2 * 256 + c]));
        float v13 = fmaxf(v5, fmaxf(bf2f(rm5[wm4 * 256 + c]),
                                    bf2f(rm5[wp4 * 256 + c])));
        q0[off] = f2bf(v5);  q1[off] = f2bf(v9);  q2[off] = f2bf(v13);
        q3[off] = f2bf(s5);  q4[off] = f2bf(s9);  q5[off] = f2bf(s13);
        if (w + 3 <= 63) s5  += bf2f(x1s[(w + 3) * 256 + c]);
        if (w - 2 >= 0)  s5  -= bf2f(x1s[(w - 2) * 256 + c]);
        if (w + 5 <= 63) s9  += bf2f(x1s[(w + 5) * 256 + c]);
        if (w - 4 >= 0)  s9  -= bf2f(x1s[(w - 4) * 256 + c]);
        if (w + 7 <= 63) s13 += bf2f(x1s[(w + 7) * 256 + c]);
        if (w - 6 >= 0)  s13 -= bf2f(x1s[(w - 6) * 256 + c]);
    }
}

// ---------------------------------------------------------------------------
// P2: vertical (along h) pass. Template I in {0,1,2} -> radius R = 2(I+1).
// Each block handles one (b, w, c-half): max section I (van Herk, O(1)/output)
// and sum section I+3 (sliding window). grid = 1024 per instantiation.
// Padded-domain van Herk: val(i<0 or i>63) = -inf; blocks of K=2R+1 starting
// at -R; out[h] = max(suf[h-R], pre[h+R]).
// ---------------------------------------------------------------------------
template <int I>
__global__ __launch_bounds__(256) void pool_v(
    const unsigned short* __restrict__ pool, unsigned short* __restrict__ catT)
{
    constexpr int R = 2 * (I + 1);
    constexpr int K = 2 * R + 1;
    constexpr float SCL = (I == 0) ? (1.f / 25.f)
                        : (I == 1) ? (1.f / 81.f) : (1.f / 169.f);
    constexpr int MAXD = 256 * (I + 1);        // y1/y2/y3 dest col
    constexpr int SUMD = 1536 - 256 * I;       // a3/a2/a1 dest col
    const int bid = blockIdx.x;                // 8*64*2 = 1024
    const int chh = bid & 1, w = (bid >> 1) & 63, b = bid >> 7;
    const int c0 = chh * 128;
    __shared__ __align__(16) unsigned short mslab[64 * 128];
    __shared__ __align__(16) unsigned short sslab[64 * 128];
    const int tid = threadIdx.x, lane = tid & 63, wave = tid >> 6;
    const long sbase = ((long)b * 4096 + (long)w * 64) * 256 + c0;
    const unsigned short* msrc = pool + (long)I * 32768 * 256 + sbase;
    const unsigned short* ssrc = pool + (long)(I + 3) * 32768 * 256 + sbase;
#pragma unroll
    for (int j = 0; j < 4; ++j) {
        int o = j * 4096 + wave * 1024 + lane * 16;
        int hh = o >> 8, ce = (o & 255) >> 1;
        GLL(msrc + hh * 256 + ce, (char*)mslab + (j * 4096 + wave * 1024));
        GLL(ssrc + hh * 256 + ce, (char*)sslab + (j * 4096 + wave * 1024));
    }
    __syncthreads();
    const int c = tid & 127, hg = tid >> 7;
    const int h0 = hg * 32;
    const long dbase = ((long)b * 4096 + w) * 1792 + c0 + c;
    // ---- max: van Herk forward (prefix) pass ----
    float pre[32];
    {
        float run = -1e30f;
        int ph = (h0 + 2 * R - (K - 1)) % K;     // (p0+R) % K, p0 = h0+R-(K-1)
#pragma unroll
        for (int t = 0; t < 32 + K - 1; ++t) {
            int p = h0 + R - (K - 1) + t;
            if (ph == 0) run = -1e30f;
            float v = ((unsigned)p < 64u) ? bf2f(mslab[p * 128 + c]) : -1e30f;
            run = fmaxf(run, v);
            if (t >= K - 1) pre[t - (K - 1)] = run;
            ph = (ph + 1 == K) ? 0 : ph + 1;
        }
    }
    // ---- max: backward (suffix) pass + emit ----
    {
        float run = -1e30f;
        int ph = (h0 + 31 + (K - 1)) % K;        // (s0+R) % K, s0 = h0+31-R+(K-1)
#pragma unroll
        for (int t = 0; t < 32 + K - 1; ++t) {
            int s = h0 + 31 - R + (K - 1) - t;
            if (ph == K - 1) run = -1e30f;
            float v = ((unsigned)s < 64u) ? bf2f(mslab[s * 128 + c]) : -1e30f;
            run = fmaxf(run, v);
            if (t >= K - 1) {
                int h = s + R;
                catT[dbase + MAXD + (long)h * (64 * 1792)] =
                    f2bf(fmaxf(run, pre[31 + (K - 1) - t]));
            }
            ph = (ph == 0) ? K - 1 : ph - 1;
        }
    }
    // ---- sum: sliding window ----
    {
        float s = 0.f;
        int lo0 = (h0 - R >= 0) ? h0 - R : 0;
        int hi0 = (h0 + R <= 63) ? h0 + R : 63;
        for (int d = lo0; d <= hi0; ++d) s += bf2f(sslab[d * 128 + c]);
        for (int hh = 0; hh < 32; ++hh) {
            int h = h0 + hh;
            catT[dbase + SUMD + (long)h * (64 * 1792)] = f2bf(s * SCL);
            if (h + 1 + R <= 63) s += bf2f(sslab[(h + 1 + R) * 128 + c]);
            if (h - R >= 0)      s -= bf2f(sslab[(h - R) * 128 + c]);
        }
    }
}

// ---------------------------------------------------------------------------
// S1: eH scores, block = (b, w).
// ---------------------------------------------------------------------------
__global__ __launch_bounds__(256) void scores_h(
    const unsigned short* __restrict__ qk, float* __restrict__ attHlog)
{
    const int b = blockIdx.x >> 6, w = blockIdx.x & 63;
    __shared__ __align__(16) unsigned short Qs[64 * 232];
    __shared__ __align__(16) unsigned short Ks[64 * 232];
    const int tid = threadIdx.x, lane = tid & 63, wave = tid >> 6;
#pragma unroll
    for (int j = 0; j < 14; ++j) {
        int idx = tid + j * 256;
        int s = idx >= 1792;
        int id2 = idx - s * 1792;
        int row = id2 / 28, cb = id2 - row * 28;
        bf16x8 v = *(const bf16x8*)(qk + ((long)b * 4096 + row * 64 + w) * 512 +
                                    s * 224 + cb * 8);
        *(bf16x8*)((s ? Ks : Qs) + row * 232 + cb * 8) = v;
    }
    __syncthreads();
    const int m0 = wave * 16, arow = lane & 15, kc = (lane >> 4) << 3;
    f32x4 acc[4] = {};
#pragma unroll
    for (int ks = 0; ks < 7; ++ks) {
        bf16x8 af = *(const bf16x8*)(Qs + (m0 + arow) * 232 + ks * 32 + kc);
#pragma unroll
        for (int nf = 0; nf < 4; ++nf) {
            bf16x8 bv = *(const bf16x8*)(Ks + (nf * 16 + arow) * 232 + ks * 32 + kc);
            acc[nf] = MFMA(af, bv, acc[nf]);
        }
    }
    const int rb = (lane >> 4) << 2;
#pragma unroll
    for (int nf = 0; nf < 4; ++nf) {
        int g = nf * 16 + arow;
#pragma unroll
        for (int r = 0; r < 4; ++r) {
            int h = m0 + rb + r;
            float v = acc[nf][r];
            if (g == h) v = -1e30f;
            attHlog[((long)(b * 64 + h) * 64 + w) * 64 + g] = v;
        }
    }
}

// ---------------------------------------------------------------------------
// S2: eW scores + fused softmax over concat([eH, eW], 128). block = (b, h).
// ---------------------------------------------------------------------------
__global__ __launch_bounds__(256) void scores_w_softmax(
    const unsigned short* __restrict__ qk, const float* __restrict__ attHlog,
    unsigned short* __restrict__ att)
{
    const int b = blockIdx.x >> 6, h = blockIdx.x & 63;
    __shared__ __align__(16) unsigned short Qs[64 * 232];
    __shared__ __align__(16) unsigned short Ks[64 * 232];
    __shared__ float ews[64 * 65];
    const int tid = threadIdx.x, lane = tid & 63, wave = tid >> 6;
    const long nbase = (long)b * 4096 + h * 64;
#pragma unroll
    for (int j = 0; j < 14; ++j) {
        int idx = tid + j * 256;
        int s = idx >= 1792;
        int id2 = idx - s * 1792;
        int row = id2 / 28, cb = id2 - row * 28;
        bf16x8 v = *(const bf16x8*)(qk + (nbase + row) * 512 + s * 224 + cb * 8);
        *(bf16x8*)((s ? Ks : Qs) + row * 232 + cb * 8) = v;
    }
    __syncthreads();
    const int m0 = wave * 16, arow = lane & 15, kc = (lane >> 4) << 3;
    f32x4 acc[4] = {};
#pragma unroll
    for (int ks = 0; ks < 7; ++ks) {
        bf16x8 af = *(const bf16x8*)(Qs + (m0 + arow) * 232 + ks * 32 + kc);
#pragma unroll
        for (int nf = 0; nf < 4; ++nf) {
            bf16x8 bv = *(const bf16x8*)(Ks + (nf * 16 + arow) * 232 + ks * 32 + kc);
            acc[nf] = MFMA(af, bv, acc[nf]);
        }
    }
    const int rb = (lane >> 4) << 2;
#pragma unroll
    for (int nf = 0; nf < 4; ++nf)
#pragma unroll
        for (int r = 0; r < 4; ++r)
            ews[(m0 + rb + r) * 65 + nf * 16 + arow] = acc[nf][r];
    __syncthreads();
    const int wl = tid >> 2, p = tid & 3;
    float eh[16], ew[16];
    const float* hrow = attHlog + ((long)(b * 64 + h) * 64 + wl) * 64 + p * 16;
#pragma unroll
    for (int j = 0; j < 16; ++j) eh[j] = hrow[j];
#pragma unroll
    for (int j = 0; j < 16; ++j) ew[j] = ews[wl * 65 + p * 16 + j];
    float mx = -1e30f;
#pragma unroll
    for (int j = 0; j < 16; ++j) { mx = fmaxf(mx, eh[j]); mx = fmaxf(mx, ew[j]); }
    mx = fmaxf(mx, __shfl_xor(mx, 1));
    mx = fmaxf(mx, __shfl_xor(mx, 2));
    float sm = 0.f;
#pragma unroll
    for (int j = 0; j < 16; ++j) {
        eh[j] = __expf(eh[j] - mx); sm += eh[j];
        ew[j] = __expf(ew[j] - mx); sm += ew[j];
    }
    sm += __shfl_xor(sm, 1);
    sm += __shfl_xor(sm, 2);
    float inv = 1.f / sm;
    unsigned short* orow = att + ((long)(b * 64 + h) * 64 + wl) * 128;
#pragma unroll
    for (int j = 0; j < 16; ++j) orow[p * 16 + j] = f2bf(eh[j] * inv);
#pragma unroll
    for (int j = 0; j < 16; ++j) orow[64 + p * 16 + j] = f2bf(ew[j] * inv);
}

// ---------------------------------------------------------------------------
// apply_att (per batch-group of 4): grid 1024 = lbb(4) x i(64) x chunk(4).
//   MODE 0: writes partial outH (part).   MODE 1: cat = gam*(outW+part)+cat.
// ---------------------------------------------------------------------------
template <int MODE>
__global__ __launch_bounds__(256) void apply_att(
    const unsigned short* __restrict__ att, const unsigned short* __restrict__ vb,
    unsigned short* __restrict__ part, unsigned short* __restrict__ cat,
    const float* __restrict__ gamma, int b0)
{
    const int ch = blockIdx.x & 3;
    const int i  = (blockIdx.x >> 2) & 63;
    const int lbb = blockIdx.x >> 8;          // 0..3 local batch
    const int b  = b0 + lbb;
    const int c0 = ch * 448;
    __shared__ __align__(16) unsigned short As[64 * 72];
    __shared__ __align__(16) unsigned short Vs[64 * 448];
    const int tid = threadIdx.x, lane = tid & 63, wave = tid >> 6;
#pragma unroll
    for (int j = 0; j < 2; ++j) {
        int idx = tid + j * 256;
        int hh = idx >> 3, cb = idx & 7;
        long pos = (MODE == 0) ? ((long)(b * 64 + hh) * 64 + i)
                               : ((long)(b * 64 + i) * 64 + hh);
        bf16x8 v = *(const bf16x8*)(att + pos * 128 + MODE * 64 + cb * 8);
        *(bf16x8*)(As + hh * 72 + cb * 8) = v;
    }
#pragma unroll
    for (int j = 0; j < 14; ++j) {
        int idx = tid + j * 256;
        int g = idx / 56, cb = idx - g * 56;
        long n = (MODE == 0) ? ((long)lbb * 4096 + g * 64 + i)
                             : ((long)lbb * 4096 + i * 64 + g);
        bf16x8 v = *(const bf16x8*)(vb + n * 1792 + c0 + cb * 8);
        int sw = (g >> 3) & 7;
        *(bf16x8*)(Vs + g * 448 + ((cb ^ sw) << 3)) = v;
    }
    __syncthreads();
    const int arow = lane & 15, kc8 = (lane >> 4) << 3;
    const int rb = (lane >> 4) << 2;
    f32x4 acc[4][7] = {};
#pragma unroll
    for (int ks = 0; ks < 2; ++ks) {
        const int k0 = ks * 32;
        bf16x8 af[4];
#pragma unroll
        for (int m = 0; m < 4; ++m)
            af[m] = *(const bf16x8*)(As + (m * 16 + arow) * 72 + k0 + kc8);
        const int g0 = k0 + kc8;
        const int sw = (g0 >> 3) & 7;
#pragma unroll
        for (int nf = 0; nf < 7; ++nf) {
            int cl = wave * 112 + nf * 16 + arow;
            int cb = cl >> 3, clo = cl & 7;
            const unsigned short* pp = Vs + g0 * 448 + ((cb ^ sw) << 3) + clo;
            bf16x8 bv;
#pragma unroll
            for (int j = 0; j < 8; ++j) bv[j] = (short)pp[j * 448];
#pragma unroll
            for (int m = 0; m < 4; ++m)
                acc[m][nf] = MFMA(af[m], bv, acc[m][nf]);
        }
    }
    const float gam = gamma[0];
#pragma unroll
    for (int nf = 0; nf < 7; ++nf) {
        const int c = c0 + wave * 112 + nf * 16 + arow;
#pragma unroll
        for (int m = 0; m < 4; ++m) {
#pragma unroll
            for (int r = 0; r < 4; ++r) {
                const int rl = m * 16 + rb + r;
                long n = (MODE == 0) ? ((long)lbb * 4096 + rl * 64 + i)
                                     : ((long)lbb * 4096 + i * 64 + rl);
                long idx2 = n * 1792 + c;
                if (MODE == 0) {
                    part[idx2] = f2bf(acc[m][nf][r]);
                } else {
                    float pv = bf2f(part[idx2]);
                    float cv = bf2f(cat[idx2]);
                    cat[idx2] = f2bf(gam * (acc[m][nf][r] + pv) + cv);
                }
            }
        }
    }
}

// ---------------------------------------------------------------------------
// launcher
// ---------------------------------------------------------------------------
extern "C" void kernel_launch(void* const* d_in, const int* in_sizes, int n_in,
                              void* d_out, int out_size, void* d_ws, size_t ws_size,
                              hipStream_t stream)
{
    const float* x     = (const float*)d_in[0];
    const float* cv1_w = (const float*)d_in[1];
    const float* cv1_g = (const float*)d_in[2];
    const float* cv1_b = (const float*)d_in[3];
    const float* cv1_m = (const float*)d_in[4];
    const float* cv1_v = (const float*)d_in[5];
    const float* q_w   = (const float*)d_in[6];
    const float* q_b   = (const float*)d_in[7];
    const float* k_w   = (const float*)d_in[8];
    const float* k_b   = (const float*)d_in[9];
    const float* v_w   = (const float*)d_in[10];
    const float* v_b   = (const float*)d_in[11];
    const float* gamma = (const float*)d_in[12];
    const float* cv2_w = (const float*)d_in[13];
    const float* cv2_g = (const float*)d_in[14];
    const float* cv2_b = (const float*)d_in[15];
    const float* cv2_m = (const float*)d_in[16];
    const float* cv2_v = (const float*)d_in[17];

    char* ws = (char*)d_ws;
    // ---- workspace map (total 219 MiB; vbuf lives in d_out) ----
    unsigned short* wb1  = (unsigned short*)(ws + 0);          //  256x512
    unsigned short* wqk  = (unsigned short*)(ws + 262144);     //  512x1792
    unsigned short* wv   = (unsigned short*)(ws + 2097152);    // 1792x1792
    unsigned short* wc2  = (unsigned short*)(ws + 8519680);    //  512x1792
    float* sc1           = (float*)(ws + 10354688);
    float* sh1           = (float*)(ws + 10358784);
    float* sc2           = (float*)(ws + 10362880);
    float* sh2           = (float*)(ws + 10366976);
    float* qkb           = (float*)(ws + 10371072);
    unsigned short* catT = (unsigned short*)(ws + 11534336);   // 32768x1792, live to end
    const long C_OFF = 128974848;                              // 96 MiB time-shared region
    unsigned short* xT    = (unsigned short*)(ws + C_OFF);           // ph1: 32 MiB
    unsigned short* poolb = (unsigned short*)(ws + C_OFF);           // ph2: 96 MiB
    float* attHlog        = (float*)(ws + C_OFF);                    // ph3: 8 MiB
    unsigned short* attb  = (unsigned short*)(ws + C_OFF + 8388608); // ph3: 8 MiB
    unsigned short* part4 = (unsigned short*)(ws + C_OFF + 16777216);// ph3: 56 MiB/group
    float* cv2tmp         = (float*)(ws + C_OFF + 16777216);         // ph4: 64 MiB
    unsigned short* qk    = (unsigned short*)d_out;                  // 32 MiB in d_out
    unsigned short* vbuf4 = (unsigned short*)d_out;                  // 56 MiB in d_out (after qk dead)

    prep_kernel<<<2048, 256, 0, stream>>>(
        cv1_w, cv1_g, cv1_b, cv1_m, cv1_v, q_w, q_b, k_w, k_b, v_w,
        cv2_w, cv2_g, cv2_b, cv2_m, cv2_v,
        wb1, wqk, wv, wc2, sc1, sh1, sc2, sh2, qkb);

    transpose_x<<<4096, 256, 0, stream>>>(x, xT);

    // cv1: x1 = silu(bn(W1 . x)) -> catT cols [0,256)
    gemm256<0><<<dim3(128, 1), 512, 0, stream>>>(xT, 512, wb1, 512, 512,
                                                 catT, 1792, sc1, sh1);

    pool_h<<<512, 256, 0, stream>>>(catT, poolb);
    pool_v<0><<<1024, 256, 0, stream>>>(poolb, catT);
    pool_v<1><<<1024, 256, 0, stream>>>(poolb, catT);
    pool_v<2><<<1024, 256, 0, stream>>>(poolb, catT);

    // q,k (stacked, padded to 512 cols) -> qk (in d_out)
    gemm256<1><<<dim3(128, 2), 512, 0, stream>>>(catT, 1792, wqk, 1792, 1792,
                                                 qk, 512, qkb, nullptr);

    scores_h<<<512, 256, 0, stream>>>(qk, attHlog);
    scores_w_softmax<<<512, 256, 0, stream>>>(qk, attHlog, attb);

    // per batch-group of 4: v GEMM + criss-cross apply (in-place into catT)
    for (int g4 = 0; g4 < 2; ++g4) {
        const unsigned short* Ap = catT + (long)g4 * 16384 * 1792;
        unsigned short* catp     = catT + (long)g4 * 16384 * 1792;
        gemm256<1><<<dim3(64, 7), 512, 0, stream>>>(Ap, 1792, wv, 1792, 1792,
                                                    vbuf4, 1792, v_b, nullptr);
        apply_att<0><<<1024, 256, 0, stream>>>(attb, vbuf4, part4, catp, gamma, g4 * 4);
        apply_att<1><<<1024, 256, 0, stream>>>(attb, vbuf4, part4, catp, gamma, g4 * 4);
    }

    // cv2: silu(bn(W2 . att)) -> fp32 tmp, then transpose to NCHW
    gemm256<2><<<dim3(128, 2), 512, 0, stream>>>(catT, 1792, wc2, 1792, 1792,
                                                 cv2tmp, 512, sc2, sh2);
    transpose_out<<<4096, 256, 0, stream>>>(cv2tmp, (float*)d_out);
}